// Round 6
// baseline (542.003 us; speedup 1.0000x reference)
//
#include <hip/hip_runtime.h>
#include <cstdint>
#include <cstddef>

// Problem constants: B=4, C=256, H=60, W=80, N=4800
#define BQ 4
#define CDIM 256
#define HH 60
#define WW 80
#define NP 4800
#define NPAD 4864          // lcm pad: 38*128 = 19*256
#define BT 256             // tile rows (t, A = tar)
#define BJ 128             // tile cols (j, B = ref)
#define BK 32              // K sub-tile
#define NTT 19             // t tiles (256)
#define NTJ 38             // j tiles (128)
#define NBLK (BQ * NTJ * NTT)   // 2888, %8==0

typedef __bf16 bf16x8 __attribute__((ext_vector_type(8)));
typedef float f32x4 __attribute__((ext_vector_type(4)));
typedef unsigned short u16x8 __attribute__((ext_vector_type(8)));

// ---------------- ws layout (bytes) ----------------
#define WS_DEST 0              // bf16 2*4*4800*256*2 = 19,660,800 (dead after k_sample)
#define WS_PART 0              // uint2 4*4800*19*8 = 2,918,400 (aliases desT)
#define WS_REFB 19660800       // bf16 4*4864*256*2 = 9,961,472
#define WS_TARB 29622272       // bf16                9,961,472
#define WS_LOSS 39583744       // f32 19200 = 76,800
#define WS_REC  39660544       // f32 19200
// end 39,737,344

#define GLD16(dst, src) __builtin_amdgcn_global_load_lds( \
    (const __attribute__((address_space(1))) void*)(src), \
    (__attribute__((address_space(3))) void*)(dst), 16, 0, 0)

__device__ inline unsigned short f2bf(float f) {
  unsigned int u = __float_as_uint(f);
  return (unsigned short)((u + 0x7FFFu + ((u >> 16) & 1u)) >> 16);  // RNE
}
__device__ inline float bf2f(unsigned short s) {
  return __uint_as_float((unsigned int)s << 16);
}

// ---------------- transpose des (C, HW) f32 -> (HW, C) bf16 ----------------
// block: 64 channels x 32 hw, threads (32,8); write phase: ushort8 per thread
__global__ __launch_bounds__(256)
void k_transpose(const float* __restrict__ src, const float* __restrict__ tgt,
                 unsigned short* __restrict__ desT) {
  __shared__ float tile[64][33];
  const int z = blockIdx.z;  // tensor*4 + b
  const float* in = ((z >> 2) ? tgt : src) + (size_t)(z & 3) * CDIM * NP;
  unsigned short* out = desT + (size_t)z * NP * CDIM;
  const int hw0 = blockIdx.x * 32;
  const int c0 = blockIdx.y * 64;
  const int tx = threadIdx.x, ty = threadIdx.y;
#pragma unroll
  for (int q = 0; q < 8; ++q)
    tile[ty + q * 8][tx] = in[(size_t)(c0 + ty + q * 8) * NP + hw0 + tx];
  __syncthreads();
  const int lt = ty * 32 + tx;
  const int c2 = lt & 7;        // 8 channels each
  const int hw = lt >> 3;       // 0..31
  u16x8 o;
#pragma unroll
  for (int k = 0; k < 8; ++k) o[k] = f2bf(tile[c2 * 8 + k][hw]);
  *(u16x8*)(out + (size_t)(hw0 + hw) * CDIM + c0 + c2 * 8) = o;
}

// ---------------- bilinear sample + L2 normalize -> bf16 rows ----------------
__global__ __launch_bounds__(256)
void k_sample(const unsigned short* __restrict__ desT,
              const float* __restrict__ spts, const float* __restrict__ tpts,
              unsigned short* __restrict__ refB, unsigned short* __restrict__ tarB) {
  const int w = threadIdx.x >> 6, lane = threadIdx.x & 63;
  const int n = blockIdx.x * 4 + w;         // 0..NPAD-1
  const int b = blockIdx.y;
  const int tensor = blockIdx.z;            // 0: ref, 1: tar
  unsigned short* outRowB = (tensor ? tarB : refB) + ((size_t)b * NPAD + n) * CDIM;
  if (n >= NP) {  // zero pad rows (uniform per wave)
    *(ushort4*)(outRowB + lane * 4) = make_ushort4(0, 0, 0, 0);
    return;
  }
  const float* pts = (tensor ? tpts : spts) + ((size_t)b * NP + n) * 2;
  const float gx = pts[0], gy = pts[1];
  const float x = (gx + 1.f) * ((WW - 1) * 0.5f);
  const float y = (gy + 1.f) * ((HH - 1) * 0.5f);
  float x0f = fminf(fmaxf(floorf(x), 0.f), (float)(WW - 1));
  float y0f = fminf(fmaxf(floorf(y), 0.f), (float)(HH - 1));
  float x1f = fminf(x0f + 1.f, (float)(WW - 1));
  float y1f = fminf(y0f + 1.f, (float)(HH - 1));
  const float wx = x - x0f, wy = y - y0f;
  const int ix0 = (int)x0f, ix1 = (int)x1f, iy0 = (int)y0f, iy1 = (int)y1f;
  const unsigned short* base = desT + (size_t)(tensor * 4 + b) * NP * CDIM + lane * 4;
  const ushort4 u00 = *(const ushort4*)(base + (size_t)(iy0 * WW + ix0) * CDIM);
  const ushort4 u01 = *(const ushort4*)(base + (size_t)(iy0 * WW + ix1) * CDIM);
  const ushort4 u10 = *(const ushort4*)(base + (size_t)(iy1 * WW + ix0) * CDIM);
  const ushort4 u11 = *(const ushort4*)(base + (size_t)(iy1 * WW + ix1) * CDIM);
  const float w00 = (1.f - wx) * (1.f - wy), w01 = wx * (1.f - wy);
  const float w10 = (1.f - wx) * wy,         w11 = wx * wy;
  float4 v;
  v.x = bf2f(u00.x) * w00 + bf2f(u01.x) * w01 + bf2f(u10.x) * w10 + bf2f(u11.x) * w11;
  v.y = bf2f(u00.y) * w00 + bf2f(u01.y) * w01 + bf2f(u10.y) * w10 + bf2f(u11.y) * w11;
  v.z = bf2f(u00.z) * w00 + bf2f(u01.z) * w01 + bf2f(u10.z) * w10 + bf2f(u11.z) * w11;
  v.w = bf2f(u00.w) * w00 + bf2f(u01.w) * w01 + bf2f(u10.w) * w10 + bf2f(u11.w) * w11;
  float s0 = v.x + 1e-8f, s1 = v.y + 1e-8f, s2 = v.z + 1e-8f, s3 = v.w + 1e-8f;
  float sum = s0 * s0 + s1 * s1 + s2 * s2 + s3 * s3;
#pragma unroll
  for (int d = 1; d < 64; d <<= 1) sum += __shfl_xor(sum, d);
  const float inv = 1.f / (sqrtf(sum) + 1e-8f);
  *(ushort4*)(outRowB + lane * 4) =
      make_ushort4(f2bf(v.x * inv), f2bf(v.y * inv), f2bf(v.z * inv), f2bf(v.w * inv));
}

// ---------------- MFMA GEMM (256t x 128j, BK=32) + fused dual argmax ----------------
// LDS rows are 64 B (4 slots of 16 B). Zero-conflict swizzle: LDS[row][s] holds
// global slot s ^ ((row>>1)&3); any 8 consecutive reader lanes hit all 32 banks.
// red[] scratch aliases bufs[0] (dead after last K-step barrier) -> 52,224 B -> 3 blocks/CU.
struct Smem {
  char bufs[2][24576];   // per buf: A [256][64B] @0, B [128][64B] @16384
  float tc[512];         // t coords: x [0,256), y [256,512)
  float jc[256];         // j coords: x [0,128), y [128,256)
};                       // 52,224 B

__global__ __launch_bounds__(512, 6)
void k_mfma_argmax(const unsigned short* __restrict__ tarB,
                   const unsigned short* __restrict__ refB,
                   const float* __restrict__ un, const int* __restrict__ relax,
                   uint2* __restrict__ partial) {
  __shared__ Smem sm;
  const int tid = threadIdx.x;
  const int lane = tid & 63;
  const int wid = tid >> 6;

  // XCD swizzle (2888 % 8 == 0)
  const int bid = blockIdx.x;
  const int item = (bid & 7) * (NBLK / 8) + (bid >> 3);
  const int b = item / (NTJ * NTT);
  const int r2 = item - b * (NTJ * NTT);
  const int jt = r2 / NTT, tt = r2 % NTT;
  const int tbase = tt * BT, jbase = jt * BJ;
  const float* unb = un + (size_t)b * 2 * NP;

  // stage coords into LDS (before first barrier)
  {
    const int i = tid & 255;
    const int tg = tbase + i < NP ? tbase + i : NP - 1;
    sm.tc[tid] = unb[(tid < 256 ? 0 : NP) + tg];
    if (tid < 256) {
      const int i2 = tid & 127;
      const int jg = jbase + i2 < NP ? jbase + i2 : NP - 1;
      sm.jc[tid] = unb[(tid < 128 ? 0 : NP) + jg];
    }
  }

  // staging: waves 0-3 -> A (64 rows each), waves 4-7 -> B (32 rows each)
  // source slot pre-swizzled: (l&3) ^ ((l>>3)&3) == (l&3) ^ ((row>>1)&3)
  const char* aSrc = (const char*)(tarB + ((size_t)b * NPAD + tbase) * CDIM);
  const char* bSrc = (const char*)(refB + ((size_t)b * NPAD + jbase) * CDIM);
  const int srcSlot = ((lane & 3) ^ ((lane >> 3) & 3)) * 16;
  const char* gl; int ldsOff, nq;
  if (wid < 4) {
    gl = aSrc + (size_t)(wid * 64 + (lane >> 2)) * 512 + srcSlot;
    ldsOff = wid * 4096; nq = 4;
  } else {
    gl = bSrc + (size_t)((wid - 4) * 32 + (lane >> 2)) * 512 + srcSlot;
    ldsOff = 16384 + (wid - 4) * 2048; nq = 2;
  }

#define STAGE(buf, kb) do { \
    char* ldst = sm.bufs[buf] + ldsOff; \
    const char* gsp = gl + (kb) * 64; \
    _Pragma("unroll") for (int qq = 0; qq < 4; ++qq) \
      if (qq < nq) GLD16(ldst + qq * 1024, gsp + (size_t)qq * 8192); \
  } while (0)

  const int wr = wid >> 1, wc = wid & 1;   // wave: 64t x 64j
  const int l15 = lane & 15, h = lane >> 4;
  const int sx = (h ^ ((l15 >> 1) & 3)) << 4;   // swizzled read slot (per-thread const)

  f32x4 acc[4][4];
#pragma unroll
  for (int fa = 0; fa < 4; ++fa)
#pragma unroll
    for (int fb = 0; fb < 4; ++fb) acc[fa][fb] = (f32x4){0.f, 0.f, 0.f, 0.f};

  // loop-invariant LDS read bases: all fragment reads become base + imm offset
  const char* aptr = sm.bufs[0] + (wr * 64 + l15) * 64 + sx;
  const char* bptr = sm.bufs[0] + 16384 + (wc * 64 + l15) * 64 + sx;

  STAGE(0, 0);
  __syncthreads();
#pragma unroll
  for (int kb = 0; kb < 8; ++kb) {   // K = 256 = 8 * 32
    const int bo = (kb & 1) * 24576;
    if (kb < 7) STAGE((kb & 1) ^ 1, kb + 1);   // issue next-tile loads before compute
    bf16x8 af[4], bg[4];
#pragma unroll
    for (int fa = 0; fa < 4; ++fa)
      af[fa] = *(const bf16x8*)(aptr + bo + fa * 1024);
#pragma unroll
    for (int fb = 0; fb < 4; ++fb)
      bg[fb] = *(const bf16x8*)(bptr + bo + fb * 1024);
#pragma unroll
    for (int fa = 0; fa < 4; ++fa)
#pragma unroll
      for (int fb = 0; fb < 4; ++fb)
        acc[fa][fb] = __builtin_amdgcn_mfma_f32_16x16x32_bf16(af[fa], bg[fb], acc[fa][fb], 0, 0, 0);
    __syncthreads();
  }

  // ---- epilogue: packed-key dual argmax (u32: [31:13]=value bits, [12:0]=8191-t) ----
  const float rf = (float)relax[0];
  float jx[4], jy[4];
#pragma unroll
  for (int fb = 0; fb < 4; ++fb) {
    const int jl = wc * 64 + fb * 16 + l15;
    jx[fb] = sm.jc[jl]; jy[fb] = sm.jc[128 + jl];
  }
  unsigned int kA[4] = {0u, 0u, 0u, 0u}, kI[4] = {0u, 0u, 0u, 0u};
  const unsigned int tinv0 = (unsigned int)(8191 - tbase);

#define EPILOG(TAIL) \
  _Pragma("unroll") for (int fa = 0; fa < 4; ++fa) { \
    _Pragma("unroll") for (int i = 0; i < 4; ++i) { \
      const int tl = wr * 64 + fa * 16 + h * 4 + i; \
      const float tx = sm.tc[tl], ty = sm.tc[256 + tl]; \
      const unsigned int tinv = tinv0 - tl; \
      _Pragma("unroll") for (int fb = 0; fb < 4; ++fb) { \
        unsigned int key = (__float_as_uint(acc[fa][fb][i] + 2.f) & 0xFFFFE000u) | tinv; \
        if (TAIL && (tbase + tl >= NP)) key = 0u; \
        if (key > kA[fb]) kA[fb] = key; \
        const float mm = fmaxf(fabsf(tx - jx[fb]), fabsf(ty - jy[fb])); \
        const unsigned int keyI = (mm <= rf) ? 0u : key; \
        if (keyI > kI[fb]) kI[fb] = keyI; \
      } \
    } \
  }

  if (tbase + BT <= NP) { EPILOG(false) } else { EPILOG(true) }
#undef EPILOG

  // reduce over the 4 h-groups (disjoint t subsets, same j); red aliases bufs[0]
  uint2* red = (uint2*)sm.bufs[0];   // [4][128]; safe: last K-step barrier passed
#pragma unroll
  for (int fb = 0; fb < 4; ++fb) {
#pragma unroll
    for (int d = 16; d < 64; d <<= 1) {
      const unsigned int oA = __shfl_xor(kA[fb], d);
      const unsigned int oI = __shfl_xor(kI[fb], d);
      if (oA > kA[fb]) kA[fb] = oA;
      if (oI > kI[fb]) kI[fb] = oI;
    }
    if (h == 0) red[wr * 128 + wc * 64 + fb * 16 + l15] = make_uint2(kA[fb], kI[fb]);
  }
  __syncthreads();
  if (tid < 128) {
    const int jg = jbase + tid;
    if (jg < NP) {
      unsigned int a = red[tid].x, c = red[tid].y;
#pragma unroll
      for (int g = 1; g < 4; ++g) {
        if (red[g * 128 + tid].x > a) a = red[g * 128 + tid].x;
        if (red[g * 128 + tid].y > c) c = red[g * 128 + tid].y;
      }
      partial[((size_t)b * NP + jg) * NTT + tt] = make_uint2(a, c);
    }
  }
#undef STAGE
}

// ---------------- fused combine + per-point loss + recall (wave per point) ----------------
__global__ __launch_bounds__(256)
void k_loss(const unsigned short* __restrict__ refB, const unsigned short* __restrict__ tarB,
            const float* __restrict__ un, const uint2* __restrict__ partial,
            float* __restrict__ loss_arr, float* __restrict__ rec_arr) {
  const int w = threadIdx.x >> 6, lane = threadIdx.x & 63;
  const int n = blockIdx.x * 4 + w;
  const int b = blockIdx.y;
  const int bn = b * NP + n;
  unsigned int kA = 0u, kI = 0u;
  if (lane < NTT) {
    const uint2 p = partial[(size_t)bn * NTT + lane];
    kA = p.x; kI = p.y;
  }
#pragma unroll
  for (int d = 1; d < 64; d <<= 1) {
    const unsigned int oA = __shfl_xor(kA, d);
    const unsigned int oI = __shfl_xor(kI, d);
    if (oA > kA) kA = oA;
    if (oI > kI) kI = oI;
  }
  const int nn  = 8191 - (int)(kA & 0x1FFFu);
  const int neg = 8191 - (int)(kI & 0x1FFFu);
  const ushort4 rv = *(const ushort4*)(refB + ((size_t)b * NPAD + n) * CDIM + lane * 4);
  const ushort4 tv = *(const ushort4*)(tarB + ((size_t)b * NPAD + n) * CDIM + lane * 4);
  const ushort4 gv = *(const ushort4*)(tarB + ((size_t)b * NPAD + neg) * CDIM + lane * 4);
  float dp = 0.f, dn = 0.f, d;
  d = bf2f(rv.x) - bf2f(tv.x) + 1e-6f; dp += d * d;
  d = bf2f(rv.y) - bf2f(tv.y) + 1e-6f; dp += d * d;
  d = bf2f(rv.z) - bf2f(tv.z) + 1e-6f; dp += d * d;
  d = bf2f(rv.w) - bf2f(tv.w) + 1e-6f; dp += d * d;
  d = bf2f(rv.x) - bf2f(gv.x) + 1e-6f; dn += d * d;
  d = bf2f(rv.y) - bf2f(gv.y) + 1e-6f; dn += d * d;
  d = bf2f(rv.z) - bf2f(gv.z) + 1e-6f; dn += d * d;
  d = bf2f(rv.w) - bf2f(gv.w) + 1e-6f; dn += d * d;
#pragma unroll
  for (int off = 1; off < 64; off <<= 1) {
    dp += __shfl_xor(dp, off);
    dn += __shfl_xor(dn, off);
  }
  if (lane == 0) {
    const float loss = fmaxf(sqrtf(dp) - sqrtf(dn) + 0.2f, 0.f);
    const float* unb = un + (size_t)b * 2 * NP;
    const float rec = (unb[nn] == unb[n] && unb[NP + nn] == unb[NP + n]) ? 1.f : 0.f;
    loss_arr[bn] = loss;
    rec_arr[bn] = rec;
  }
}

// ---------------- final deterministic reduce ----------------
__global__ __launch_bounds__(256)
void k_finalize(const float* __restrict__ loss_arr, const float* __restrict__ rec_arr,
                float* __restrict__ out) {
  __shared__ float l[256], rr[256];
  float ls = 0.f, rs = 0.f;
  for (int i = threadIdx.x; i < BQ * NP; i += 256) { ls += loss_arr[i]; rs += rec_arr[i]; }
  l[threadIdx.x] = ls;
  rr[threadIdx.x] = rs;
  __syncthreads();
  for (int s = 128; s > 0; s >>= 1) {
    if (threadIdx.x < s) { l[threadIdx.x] += l[threadIdx.x + s]; rr[threadIdx.x] += rr[threadIdx.x + s]; }
    __syncthreads();
  }
  if (threadIdx.x == 0) {
    out[0] = l[0] / (float)(BQ * NP);
    out[1] = rr[0] / (float)(BQ * NP);
  }
}

extern "C" void kernel_launch(void* const* d_in, const int* in_sizes, int n_in,
                              void* d_out, int out_size, void* d_ws, size_t ws_size,
                              hipStream_t stream) {
  const float* src  = (const float*)d_in[0];
  const float* tgt  = (const float*)d_in[1];
  const float* spts = (const float*)d_in[2];
  const float* tpts = (const float*)d_in[3];
  const float* un   = (const float*)d_in[4];
  const int* relax  = (const int*)d_in[5];

  char* ws = (char*)d_ws;
  unsigned short* desT     = (unsigned short*)(ws + WS_DEST);
  uint2*          partial  = (uint2*)(ws + WS_PART);   // aliases desT (dead by then)
  unsigned short* refB     = (unsigned short*)(ws + WS_REFB);
  unsigned short* tarB     = (unsigned short*)(ws + WS_TARB);
  float*          loss_arr = (float*)(ws + WS_LOSS);
  float*          rec_arr  = (float*)(ws + WS_REC);
  float*          out      = (float*)d_out;

  k_transpose<<<dim3(NP / 32, CDIM / 64, 8), dim3(32, 8), 0, stream>>>(src, tgt, desT);
  k_sample<<<dim3(NPAD / 4, BQ, 2), 256, 0, stream>>>(desT, spts, tpts, refB, tarB);
  k_mfma_argmax<<<NBLK, 512, 0, stream>>>(tarB, refB, un, relax, partial);
  k_loss<<<dim3(NP / 4, BQ), 256, 0, stream>>>(refB, tarB, un, partial, loss_arr, rec_arr);
  k_finalize<<<1, 256, 0, stream>>>(loss_arr, rec_arr, out);
}

// Round 7
// 132.538 us; speedup vs baseline: 4.0894x; 4.0894x over previous
//
#include <hip/hip_runtime.h>
#include <cstdint>
#include <cstddef>

// Problem constants: B=4, C=256, H=60, W=80, N=4800
#define BQ 4
#define CDIM 256
#define HH 60
#define WW 80
#define NP 4800
#define NPAD 4864          // lcm pad: 38*128 = 19*256
#define BT 256             // tile rows (t, A = tar)
#define BJ 128             // tile cols (j, B = ref)
#define BK 32              // K sub-tile
#define NTT 19             // t tiles (256)
#define NTJ 38             // j tiles (128)
#define NBLK (BQ * NTJ * NTT)   // 2888, %8==0

typedef __bf16 bf16x8 __attribute__((ext_vector_type(8)));
typedef float f32x4 __attribute__((ext_vector_type(4)));
typedef unsigned short u16x8 __attribute__((ext_vector_type(8)));

// ---------------- ws layout (bytes) ----------------
#define WS_DEST 0              // bf16 2*4*4800*256*2 = 19,660,800 (dead after k_sample)
#define WS_PART 0              // uint2 4*4800*19*8 = 2,918,400 (aliases desT)
#define WS_REFB 19660800       // bf16 4*4864*256*2 = 9,961,472
#define WS_TARB 29622272       // bf16                9,961,472
#define WS_LOSS 39583744       // f32 19200 = 76,800
#define WS_REC  39660544       // f32 19200
// end 39,737,344

#define GLD16(dst, src) __builtin_amdgcn_global_load_lds( \
    (const __attribute__((address_space(1))) void*)(src), \
    (__attribute__((address_space(3))) void*)(dst), 16, 0, 0)

__device__ inline unsigned short f2bf(float f) {
  unsigned int u = __float_as_uint(f);
  return (unsigned short)((u + 0x7FFFu + ((u >> 16) & 1u)) >> 16);  // RNE
}
__device__ inline float bf2f(unsigned short s) {
  return __uint_as_float((unsigned int)s << 16);
}

// ---------------- transpose des (C, HW) f32 -> (HW, C) bf16 ----------------
// block: 64 channels x 32 hw, threads (32,8); write phase: ushort8 per thread
__global__ __launch_bounds__(256)
void k_transpose(const float* __restrict__ src, const float* __restrict__ tgt,
                 unsigned short* __restrict__ desT) {
  __shared__ float tile[64][33];
  const int z = blockIdx.z;  // tensor*4 + b
  const float* in = ((z >> 2) ? tgt : src) + (size_t)(z & 3) * CDIM * NP;
  unsigned short* out = desT + (size_t)z * NP * CDIM;
  const int hw0 = blockIdx.x * 32;
  const int c0 = blockIdx.y * 64;
  const int tx = threadIdx.x, ty = threadIdx.y;
#pragma unroll
  for (int q = 0; q < 8; ++q)
    tile[ty + q * 8][tx] = in[(size_t)(c0 + ty + q * 8) * NP + hw0 + tx];
  __syncthreads();
  const int lt = ty * 32 + tx;
  const int c2 = lt & 7;        // 8 channels each
  const int hw = lt >> 3;       // 0..31
  u16x8 o;
#pragma unroll
  for (int k = 0; k < 8; ++k) o[k] = f2bf(tile[c2 * 8 + k][hw]);
  *(u16x8*)(out + (size_t)(hw0 + hw) * CDIM + c0 + c2 * 8) = o;
}

// ---------------- bilinear sample + L2 normalize -> bf16 rows ----------------
__global__ __launch_bounds__(256)
void k_sample(const unsigned short* __restrict__ desT,
              const float* __restrict__ spts, const float* __restrict__ tpts,
              unsigned short* __restrict__ refB, unsigned short* __restrict__ tarB) {
  const int w = threadIdx.x >> 6, lane = threadIdx.x & 63;
  const int n = blockIdx.x * 4 + w;         // 0..NPAD-1
  const int b = blockIdx.y;
  const int tensor = blockIdx.z;            // 0: ref, 1: tar
  unsigned short* outRowB = (tensor ? tarB : refB) + ((size_t)b * NPAD + n) * CDIM;
  if (n >= NP) {  // zero pad rows (uniform per wave)
    *(ushort4*)(outRowB + lane * 4) = make_ushort4(0, 0, 0, 0);
    return;
  }
  const float* pts = (tensor ? tpts : spts) + ((size_t)b * NP + n) * 2;
  const float gx = pts[0], gy = pts[1];
  const float x = (gx + 1.f) * ((WW - 1) * 0.5f);
  const float y = (gy + 1.f) * ((HH - 1) * 0.5f);
  float x0f = fminf(fmaxf(floorf(x), 0.f), (float)(WW - 1));
  float y0f = fminf(fmaxf(floorf(y), 0.f), (float)(HH - 1));
  float x1f = fminf(x0f + 1.f, (float)(WW - 1));
  float y1f = fminf(y0f + 1.f, (float)(HH - 1));
  const float wx = x - x0f, wy = y - y0f;
  const int ix0 = (int)x0f, ix1 = (int)x1f, iy0 = (int)y0f, iy1 = (int)y1f;
  const unsigned short* base = desT + (size_t)(tensor * 4 + b) * NP * CDIM + lane * 4;
  const ushort4 u00 = *(const ushort4*)(base + (size_t)(iy0 * WW + ix0) * CDIM);
  const ushort4 u01 = *(const ushort4*)(base + (size_t)(iy0 * WW + ix1) * CDIM);
  const ushort4 u10 = *(const ushort4*)(base + (size_t)(iy1 * WW + ix0) * CDIM);
  const ushort4 u11 = *(const ushort4*)(base + (size_t)(iy1 * WW + ix1) * CDIM);
  const float w00 = (1.f - wx) * (1.f - wy), w01 = wx * (1.f - wy);
  const float w10 = (1.f - wx) * wy,         w11 = wx * wy;
  float4 v;
  v.x = bf2f(u00.x) * w00 + bf2f(u01.x) * w01 + bf2f(u10.x) * w10 + bf2f(u11.x) * w11;
  v.y = bf2f(u00.y) * w00 + bf2f(u01.y) * w01 + bf2f(u10.y) * w10 + bf2f(u11.y) * w11;
  v.z = bf2f(u00.z) * w00 + bf2f(u01.z) * w01 + bf2f(u10.z) * w10 + bf2f(u11.z) * w11;
  v.w = bf2f(u00.w) * w00 + bf2f(u01.w) * w01 + bf2f(u10.w) * w10 + bf2f(u11.w) * w11;
  float s0 = v.x + 1e-8f, s1 = v.y + 1e-8f, s2 = v.z + 1e-8f, s3 = v.w + 1e-8f;
  float sum = s0 * s0 + s1 * s1 + s2 * s2 + s3 * s3;
#pragma unroll
  for (int d = 1; d < 64; d <<= 1) sum += __shfl_xor(sum, d);
  const float inv = 1.f / (sqrtf(sum) + 1e-8f);
  *(ushort4*)(outRowB + lane * 4) =
      make_ushort4(f2bf(v.x * inv), f2bf(v.y * inv), f2bf(v.z * inv), f2bf(v.w * inv));
}

// ---------------- MFMA GEMM (256t x 128j, BK=32) + fused dual argmax ----------------
// LDS rows are 64 B (4 slots of 16 B). Zero-conflict swizzle: LDS[row][s] holds
// global slot s ^ ((row>>1)&3); any 8 consecutive reader lanes hit all 32 banks.
// red[] scratch aliases bufs[0] (dead after last K-step barrier).
// launch_bounds (512,4): 2 blocks/CU. (512,6) forced <=85 VGPR -> acc spilled to
// scratch -> 3.5 GB HBM spill traffic, 7x slowdown (round-6 lesson). 3 blocks/CU
// is structurally impossible with a 64-reg accumulator: 512/6 < 64+fragments.
struct Smem {
  char bufs[2][24576];   // per buf: A [256][64B] @0, B [128][64B] @16384
  float tc[512];         // t coords: x [0,256), y [256,512)
  float jc[256];         // j coords: x [0,128), y [128,256)
};                       // 52,224 B

__global__ __launch_bounds__(512, 4)
void k_mfma_argmax(const unsigned short* __restrict__ tarB,
                   const unsigned short* __restrict__ refB,
                   const float* __restrict__ un, const int* __restrict__ relax,
                   uint2* __restrict__ partial) {
  __shared__ Smem sm;
  const int tid = threadIdx.x;
  const int lane = tid & 63;
  const int wid = tid >> 6;

  // XCD swizzle (2888 % 8 == 0)
  const int bid = blockIdx.x;
  const int item = (bid & 7) * (NBLK / 8) + (bid >> 3);
  const int b = item / (NTJ * NTT);
  const int r2 = item - b * (NTJ * NTT);
  const int jt = r2 / NTT, tt = r2 % NTT;
  const int tbase = tt * BT, jbase = jt * BJ;
  const float* unb = un + (size_t)b * 2 * NP;

  // stage coords into LDS (before first barrier)
  {
    const int i = tid & 255;
    const int tg = tbase + i < NP ? tbase + i : NP - 1;
    sm.tc[tid] = unb[(tid < 256 ? 0 : NP) + tg];
    if (tid < 256) {
      const int i2 = tid & 127;
      const int jg = jbase + i2 < NP ? jbase + i2 : NP - 1;
      sm.jc[tid] = unb[(tid < 128 ? 0 : NP) + jg];
    }
  }

  // staging: waves 0-3 -> A (64 rows each), waves 4-7 -> B (32 rows each)
  // source slot pre-swizzled: (l&3) ^ ((l>>3)&3) == (l&3) ^ ((row>>1)&3)
  const char* aSrc = (const char*)(tarB + ((size_t)b * NPAD + tbase) * CDIM);
  const char* bSrc = (const char*)(refB + ((size_t)b * NPAD + jbase) * CDIM);
  const int srcSlot = ((lane & 3) ^ ((lane >> 3) & 3)) * 16;
  const char* gl; int ldsOff, nq;
  if (wid < 4) {
    gl = aSrc + (size_t)(wid * 64 + (lane >> 2)) * 512 + srcSlot;
    ldsOff = wid * 4096; nq = 4;
  } else {
    gl = bSrc + (size_t)((wid - 4) * 32 + (lane >> 2)) * 512 + srcSlot;
    ldsOff = 16384 + (wid - 4) * 2048; nq = 2;
  }

#define STAGE(buf, kb) do { \
    char* ldst = sm.bufs[buf] + ldsOff; \
    const char* gsp = gl + (kb) * 64; \
    _Pragma("unroll") for (int qq = 0; qq < 4; ++qq) \
      if (qq < nq) GLD16(ldst + qq * 1024, gsp + (size_t)qq * 8192); \
  } while (0)

  const int wr = wid >> 1, wc = wid & 1;   // wave: 64t x 64j
  const int l15 = lane & 15, h = lane >> 4;
  const int sx = (h ^ ((l15 >> 1) & 3)) << 4;   // swizzled read slot (per-thread const)

  f32x4 acc[4][4];
#pragma unroll
  for (int fa = 0; fa < 4; ++fa)
#pragma unroll
    for (int fb = 0; fb < 4; ++fb) acc[fa][fb] = (f32x4){0.f, 0.f, 0.f, 0.f};

  // loop-invariant LDS read bases: all fragment reads become base + imm offset
  const char* aptr = sm.bufs[0] + (wr * 64 + l15) * 64 + sx;
  const char* bptr = sm.bufs[0] + 16384 + (wc * 64 + l15) * 64 + sx;

  STAGE(0, 0);
  __syncthreads();
#pragma unroll
  for (int kb = 0; kb < 8; ++kb) {   // K = 256 = 8 * 32
    const int bo = (kb & 1) * 24576;
    if (kb < 7) STAGE((kb & 1) ^ 1, kb + 1);   // issue next-tile loads before compute
    bf16x8 af[4], bg[4];
#pragma unroll
    for (int fa = 0; fa < 4; ++fa)
      af[fa] = *(const bf16x8*)(aptr + bo + fa * 1024);
#pragma unroll
    for (int fb = 0; fb < 4; ++fb)
      bg[fb] = *(const bf16x8*)(bptr + bo + fb * 1024);
#pragma unroll
    for (int fa = 0; fa < 4; ++fa)
#pragma unroll
      for (int fb = 0; fb < 4; ++fb)
        acc[fa][fb] = __builtin_amdgcn_mfma_f32_16x16x32_bf16(af[fa], bg[fb], acc[fa][fb], 0, 0, 0);
    __syncthreads();
  }

  // ---- epilogue: packed-key dual argmax (u32: [31:13]=value bits, [12:0]=8191-t) ----
  const float rf = (float)relax[0];
  float jx[4], jy[4];
#pragma unroll
  for (int fb = 0; fb < 4; ++fb) {
    const int jl = wc * 64 + fb * 16 + l15;
    jx[fb] = sm.jc[jl]; jy[fb] = sm.jc[128 + jl];
  }
  unsigned int kA[4] = {0u, 0u, 0u, 0u}, kI[4] = {0u, 0u, 0u, 0u};
  const unsigned int tinv0 = (unsigned int)(8191 - tbase);

#define EPILOG(TAIL) \
  _Pragma("unroll") for (int fa = 0; fa < 4; ++fa) { \
    _Pragma("unroll") for (int i = 0; i < 4; ++i) { \
      const int tl = wr * 64 + fa * 16 + h * 4 + i; \
      const float tx = sm.tc[tl], ty = sm.tc[256 + tl]; \
      const unsigned int tinv = tinv0 - tl; \
      _Pragma("unroll") for (int fb = 0; fb < 4; ++fb) { \
        unsigned int key = (__float_as_uint(acc[fa][fb][i] + 2.f) & 0xFFFFE000u) | tinv; \
        if (TAIL && (tbase + tl >= NP)) key = 0u; \
        if (key > kA[fb]) kA[fb] = key; \
        const float mm = fmaxf(fabsf(tx - jx[fb]), fabsf(ty - jy[fb])); \
        const unsigned int keyI = (mm <= rf) ? 0u : key; \
        if (keyI > kI[fb]) kI[fb] = keyI; \
      } \
    } \
  }

  if (tbase + BT <= NP) { EPILOG(false) } else { EPILOG(true) }
#undef EPILOG

  // reduce over the 4 h-groups (disjoint t subsets, same j); red aliases bufs[0]
  uint2* red = (uint2*)sm.bufs[0];   // [4][128]; safe: last K-step barrier passed
#pragma unroll
  for (int fb = 0; fb < 4; ++fb) {
#pragma unroll
    for (int d = 16; d < 64; d <<= 1) {
      const unsigned int oA = __shfl_xor(kA[fb], d);
      const unsigned int oI = __shfl_xor(kI[fb], d);
      if (oA > kA[fb]) kA[fb] = oA;
      if (oI > kI[fb]) kI[fb] = oI;
    }
    if (h == 0) red[wr * 128 + wc * 64 + fb * 16 + l15] = make_uint2(kA[fb], kI[fb]);
  }
  __syncthreads();
  if (tid < 128) {
    const int jg = jbase + tid;
    if (jg < NP) {
      unsigned int a = red[tid].x, c = red[tid].y;
#pragma unroll
      for (int g = 1; g < 4; ++g) {
        if (red[g * 128 + tid].x > a) a = red[g * 128 + tid].x;
        if (red[g * 128 + tid].y > c) c = red[g * 128 + tid].y;
      }
      partial[((size_t)b * NP + jg) * NTT + tt] = make_uint2(a, c);
    }
  }
#undef STAGE
}

// ---------------- fused combine + per-point loss + recall (wave per point) ----------------
__global__ __launch_bounds__(256)
void k_loss(const unsigned short* __restrict__ refB, const unsigned short* __restrict__ tarB,
            const float* __restrict__ un, const uint2* __restrict__ partial,
            float* __restrict__ loss_arr, float* __restrict__ rec_arr) {
  const int w = threadIdx.x >> 6, lane = threadIdx.x & 63;
  const int n = blockIdx.x * 4 + w;
  const int b = blockIdx.y;
  const int bn = b * NP + n;
  unsigned int kA = 0u, kI = 0u;
  if (lane < NTT) {
    const uint2 p = partial[(size_t)bn * NTT + lane];
    kA = p.x; kI = p.y;
  }
#pragma unroll
  for (int d = 1; d < 64; d <<= 1) {
    const unsigned int oA = __shfl_xor(kA, d);
    const unsigned int oI = __shfl_xor(kI, d);
    if (oA > kA) kA = oA;
    if (oI > kI) kI = oI;
  }
  const int nn  = 8191 - (int)(kA & 0x1FFFu);
  const int neg = 8191 - (int)(kI & 0x1FFFu);
  const ushort4 rv = *(const ushort4*)(refB + ((size_t)b * NPAD + n) * CDIM + lane * 4);
  const ushort4 tv = *(const ushort4*)(tarB + ((size_t)b * NPAD + n) * CDIM + lane * 4);
  const ushort4 gv = *(const ushort4*)(tarB + ((size_t)b * NPAD + neg) * CDIM + lane * 4);
  float dp = 0.f, dn = 0.f, d;
  d = bf2f(rv.x) - bf2f(tv.x) + 1e-6f; dp += d * d;
  d = bf2f(rv.y) - bf2f(tv.y) + 1e-6f; dp += d * d;
  d = bf2f(rv.z) - bf2f(tv.z) + 1e-6f; dp += d * d;
  d = bf2f(rv.w) - bf2f(tv.w) + 1e-6f; dp += d * d;
  d = bf2f(rv.x) - bf2f(gv.x) + 1e-6f; dn += d * d;
  d = bf2f(rv.y) - bf2f(gv.y) + 1e-6f; dn += d * d;
  d = bf2f(rv.z) - bf2f(gv.z) + 1e-6f; dn += d * d;
  d = bf2f(rv.w) - bf2f(gv.w) + 1e-6f; dn += d * d;
#pragma unroll
  for (int off = 1; off < 64; off <<= 1) {
    dp += __shfl_xor(dp, off);
    dn += __shfl_xor(dn, off);
  }
  if (lane == 0) {
    const float loss = fmaxf(sqrtf(dp) - sqrtf(dn) + 0.2f, 0.f);
    const float* unb = un + (size_t)b * 2 * NP;
    const float rec = (unb[nn] == unb[n] && unb[NP + nn] == unb[NP + n]) ? 1.f : 0.f;
    loss_arr[bn] = loss;
    rec_arr[bn] = rec;
  }
}

// ---------------- final deterministic reduce ----------------
__global__ __launch_bounds__(256)
void k_finalize(const float* __restrict__ loss_arr, const float* __restrict__ rec_arr,
                float* __restrict__ out) {
  __shared__ float l[256], rr[256];
  float ls = 0.f, rs = 0.f;
  for (int i = threadIdx.x; i < BQ * NP; i += 256) { ls += loss_arr[i]; rs += rec_arr[i]; }
  l[threadIdx.x] = ls;
  rr[threadIdx.x] = rs;
  __syncthreads();
  for (int s = 128; s > 0; s >>= 1) {
    if (threadIdx.x < s) { l[threadIdx.x] += l[threadIdx.x + s]; rr[threadIdx.x] += rr[threadIdx.x + s]; }
    __syncthreads();
  }
  if (threadIdx.x == 0) {
    out[0] = l[0] / (float)(BQ * NP);
    out[1] = rr[0] / (float)(BQ * NP);
  }
}

extern "C" void kernel_launch(void* const* d_in, const int* in_sizes, int n_in,
                              void* d_out, int out_size, void* d_ws, size_t ws_size,
                              hipStream_t stream) {
  const float* src  = (const float*)d_in[0];
  const float* tgt  = (const float*)d_in[1];
  const float* spts = (const float*)d_in[2];
  const float* tpts = (const float*)d_in[3];
  const float* un   = (const float*)d_in[4];
  const int* relax  = (const int*)d_in[5];

  char* ws = (char*)d_ws;
  unsigned short* desT     = (unsigned short*)(ws + WS_DEST);
  uint2*          partial  = (uint2*)(ws + WS_PART);   // aliases desT (dead by then)
  unsigned short* refB     = (unsigned short*)(ws + WS_REFB);
  unsigned short* tarB     = (unsigned short*)(ws + WS_TARB);
  float*          loss_arr = (float*)(ws + WS_LOSS);
  float*          rec_arr  = (float*)(ws + WS_REC);
  float*          out      = (float*)d_out;

  k_transpose<<<dim3(NP / 32, CDIM / 64, 8), dim3(32, 8), 0, stream>>>(src, tgt, desT);
  k_sample<<<dim3(NPAD / 4, BQ, 2), 256, 0, stream>>>(desT, spts, tpts, refB, tarB);
  k_mfma_argmax<<<NBLK, 512, 0, stream>>>(tarB, refB, un, relax, partial);
  k_loss<<<dim3(NP / 4, BQ), 256, 0, stream>>>(refB, tarB, un, partial, loss_arr, rec_arr);
  k_finalize<<<1, 256, 0, stream>>>(loss_arr, rec_arr, out);
}

// Round 8
// 119.605 us; speedup vs baseline: 4.5316x; 1.1081x over previous
//
#include <hip/hip_runtime.h>
#include <cstdint>
#include <cstddef>

// Problem constants: B=4, C=256, H=60, W=80, N=4800
#define BQ 4
#define CDIM 256
#define HH 60
#define WW 80
#define NP 4800
#define NPAD 4864          // lcm pad: 38*128 = 19*256
#define BT 256             // tile rows (t, A = tar)
#define BJ 128             // tile cols (j, B = ref)
#define NTT 19             // t tiles (256)
#define NTJ 38             // j tiles (128)
#define NBLK (BQ * NTJ * NTT)   // 2888, %8==0

typedef float f32x4 __attribute__((ext_vector_type(4)));
typedef unsigned short u16x8 __attribute__((ext_vector_type(8)));

// ---------------- ws layout (bytes) ----------------
#define WS_DEST 0              // bf16 2*4*4800*256*2 = 19,660,800 (dead after k_sample)
#define WS_PART 0              // uint2 4*4800*19*8 = 2,918,400 (aliases desT)
#define WS_REFB 19660800       // bf16 4*4864*256*2 = 9,961,472 (for k_loss)
#define WS_TARB 29622272       // bf16                9,961,472
#define WS_REFQ 39583744       // fp8 4*4864*256 = 4,980,736 (for GEMM)
#define WS_TARQ 44564480       // fp8                4,980,736
#define WS_LOSS 49545216       // f32 19200 = 76,800
#define WS_REC  49622016       // f32 19200
// end 49,698,816

#define GLD16(dst, src) __builtin_amdgcn_global_load_lds( \
    (const __attribute__((address_space(1))) void*)(src), \
    (__attribute__((address_space(3))) void*)(dst), 16, 0, 0)

__device__ inline unsigned short f2bf(float f) {
  unsigned int u = __float_as_uint(f);
  return (unsigned short)((u + 0x7FFFu + ((u >> 16) & 1u)) >> 16);  // RNE
}
__device__ inline float bf2f(unsigned short s) {
  return __uint_as_float((unsigned int)s << 16);
}
// f32 -> OCP e4m3fn, RNE, clamp to +-448, subnormals handled
__device__ inline unsigned char f2e4m3(float x) {
  float ax = fminf(fabsf(x), 448.f);
  const unsigned int sign = (__float_as_uint(x) >> 24) & 0x80u;
  if (ax < 0.015625f) {                     // below 2^-6: subnormal (or carry to 0x08)
    const int M = (int)rintf(ax * 512.f);   // 0..8; 8 == 2^-6 encodes as E=1,M=0
    return (unsigned char)(sign | (unsigned int)M);
  }
  unsigned int u = __float_as_uint(ax);
  u += 0x7FFFFu + ((u >> 20) & 1u);         // RNE at mantissa bit 20 (carry ok)
  unsigned int e = (u >> 23) - 120u;        // exp bias 127 -> 7
  unsigned int m = (u >> 20) & 7u;
  if (e >= 16u) { e = 15u; m = 6u; }        // clamp to 448 (rounding overshoot)
  return (unsigned char)(sign | (e << 3) | m);
}

// ---------------- transpose des (C, HW) f32 -> (HW, C) bf16 ----------------
__global__ __launch_bounds__(256)
void k_transpose(const float* __restrict__ src, const float* __restrict__ tgt,
                 unsigned short* __restrict__ desT) {
  __shared__ float tile[64][33];
  const int z = blockIdx.z;  // tensor*4 + b
  const float* in = ((z >> 2) ? tgt : src) + (size_t)(z & 3) * CDIM * NP;
  unsigned short* out = desT + (size_t)z * NP * CDIM;
  const int hw0 = blockIdx.x * 32;
  const int c0 = blockIdx.y * 64;
  const int tx = threadIdx.x, ty = threadIdx.y;
#pragma unroll
  for (int q = 0; q < 8; ++q)
    tile[ty + q * 8][tx] = in[(size_t)(c0 + ty + q * 8) * NP + hw0 + tx];
  __syncthreads();
  const int lt = ty * 32 + tx;
  const int c2 = lt & 7;        // 8 channels each
  const int hw = lt >> 3;       // 0..31
  u16x8 o;
#pragma unroll
  for (int k = 0; k < 8; ++k) o[k] = f2bf(tile[c2 * 8 + k][hw]);
  *(u16x8*)(out + (size_t)(hw0 + hw) * CDIM + c0 + c2 * 8) = o;
}

// ---------------- bilinear sample + L2 normalize -> bf16 rows + fp8(x16) rows ----------------
__global__ __launch_bounds__(256)
void k_sample(const unsigned short* __restrict__ desT,
              const float* __restrict__ spts, const float* __restrict__ tpts,
              unsigned short* __restrict__ refB, unsigned short* __restrict__ tarB,
              unsigned char* __restrict__ refQ, unsigned char* __restrict__ tarQ) {
  const int w = threadIdx.x >> 6, lane = threadIdx.x & 63;
  const int n = blockIdx.x * 4 + w;         // 0..NPAD-1
  const int b = blockIdx.y;
  const int tensor = blockIdx.z;            // 0: ref, 1: tar
  unsigned short* outRowB = (tensor ? tarB : refB) + ((size_t)b * NPAD + n) * CDIM;
  unsigned char*  outRowQ = (tensor ? tarQ : refQ) + ((size_t)b * NPAD + n) * CDIM;
  if (n >= NP) {  // zero pad rows (uniform per wave)
    *(ushort4*)(outRowB + lane * 4) = make_ushort4(0, 0, 0, 0);
    *(uchar4*)(outRowQ + lane * 4) = make_uchar4(0, 0, 0, 0);
    return;
  }
  const float* pts = (tensor ? tpts : spts) + ((size_t)b * NP + n) * 2;
  const float gx = pts[0], gy = pts[1];
  const float x = (gx + 1.f) * ((WW - 1) * 0.5f);
  const float y = (gy + 1.f) * ((HH - 1) * 0.5f);
  float x0f = fminf(fmaxf(floorf(x), 0.f), (float)(WW - 1));
  float y0f = fminf(fmaxf(floorf(y), 0.f), (float)(HH - 1));
  float x1f = fminf(x0f + 1.f, (float)(WW - 1));
  float y1f = fminf(y0f + 1.f, (float)(HH - 1));
  const float wx = x - x0f, wy = y - y0f;
  const int ix0 = (int)x0f, ix1 = (int)x1f, iy0 = (int)y0f, iy1 = (int)y1f;
  const unsigned short* base = desT + (size_t)(tensor * 4 + b) * NP * CDIM + lane * 4;
  const ushort4 u00 = *(const ushort4*)(base + (size_t)(iy0 * WW + ix0) * CDIM);
  const ushort4 u01 = *(const ushort4*)(base + (size_t)(iy0 * WW + ix1) * CDIM);
  const ushort4 u10 = *(const ushort4*)(base + (size_t)(iy1 * WW + ix0) * CDIM);
  const ushort4 u11 = *(const ushort4*)(base + (size_t)(iy1 * WW + ix1) * CDIM);
  const float w00 = (1.f - wx) * (1.f - wy), w01 = wx * (1.f - wy);
  const float w10 = (1.f - wx) * wy,         w11 = wx * wy;
  float4 v;
  v.x = bf2f(u00.x) * w00 + bf2f(u01.x) * w01 + bf2f(u10.x) * w10 + bf2f(u11.x) * w11;
  v.y = bf2f(u00.y) * w00 + bf2f(u01.y) * w01 + bf2f(u10.y) * w10 + bf2f(u11.y) * w11;
  v.z = bf2f(u00.z) * w00 + bf2f(u01.z) * w01 + bf2f(u10.z) * w10 + bf2f(u11.z) * w11;
  v.w = bf2f(u00.w) * w00 + bf2f(u01.w) * w01 + bf2f(u10.w) * w10 + bf2f(u11.w) * w11;
  float s0 = v.x + 1e-8f, s1 = v.y + 1e-8f, s2 = v.z + 1e-8f, s3 = v.w + 1e-8f;
  float sum = s0 * s0 + s1 * s1 + s2 * s2 + s3 * s3;
#pragma unroll
  for (int d = 1; d < 64; d <<= 1) sum += __shfl_xor(sum, d);
  const float inv = 1.f / (sqrtf(sum) + 1e-8f);
  *(ushort4*)(outRowB + lane * 4) =
      make_ushort4(f2bf(v.x * inv), f2bf(v.y * inv), f2bf(v.z * inv), f2bf(v.w * inv));
  const float invq = inv * 16.f;   // scale into e4m3 normal range; dot' = 256*dot
  *(uchar4*)(outRowQ + lane * 4) =
      make_uchar4(f2e4m3(v.x * invq), f2e4m3(v.y * invq), f2e4m3(v.z * invq), f2e4m3(v.w * invq));
}

// ---------------- fp8 MFMA GEMM (256t x 128j, BK=64) + fused dual argmax ----------------
// LDS rows 64 B (= one BK=64 fp8 slice). Store slot s holds global slot s^((row>>1)&3);
// reads are ds_read_b64 at the 128 B/cy floor. red[] aliases bufs[0] after last barrier.
// launch_bounds (512,4): 2 blocks/CU. (512,6) spilled acc -> 7x regression (round-6 lesson).
struct Smem {
  char bufs[2][24576];   // per buf: A [256][64B] @0, B [128][64B] @16384
  float tc[512];         // t coords: x [0,256), y [256,512)
  float jc[256];         // j coords: x [0,128), y [128,256)
};                       // 52,224 B

__global__ __launch_bounds__(512, 4)
void k_mfma_argmax(const unsigned char* __restrict__ tarQ,
                   const unsigned char* __restrict__ refQ,
                   const float* __restrict__ un, const int* __restrict__ relax,
                   uint2* __restrict__ partial) {
  __shared__ Smem sm;
  const int tid = threadIdx.x;
  const int lane = tid & 63;
  const int wid = tid >> 6;

  // XCD swizzle (2888 % 8 == 0)
  const int bid = blockIdx.x;
  const int item = (bid & 7) * (NBLK / 8) + (bid >> 3);
  const int b = item / (NTJ * NTT);
  const int r2 = item - b * (NTJ * NTT);
  const int jt = r2 / NTT, tt = r2 % NTT;
  const int tbase = tt * BT, jbase = jt * BJ;
  const float* unb = un + (size_t)b * 2 * NP;

  // stage coords into LDS (before first barrier)
  {
    const int i = tid & 255;
    const int tg = tbase + i < NP ? tbase + i : NP - 1;
    sm.tc[tid] = unb[(tid < 256 ? 0 : NP) + tg];
    if (tid < 256) {
      const int i2 = tid & 127;
      const int jg = jbase + i2 < NP ? jbase + i2 : NP - 1;
      sm.jc[tid] = unb[(tid < 128 ? 0 : NP) + jg];
    }
  }

  // staging: waves 0-3 -> A (64 rows each), waves 4-7 -> B (32 rows each)
  // global rows are 256 B (fp8); kb selects a 64-B slice. Source slot pre-swizzled.
  const char* aSrc = (const char*)(tarQ + ((size_t)b * NPAD + tbase) * CDIM);
  const char* bSrc = (const char*)(refQ + ((size_t)b * NPAD + jbase) * CDIM);
  const int srcSlot = ((lane & 3) ^ ((lane >> 3) & 3)) * 16;
  const char* gl; int ldsOff, nq;
  if (wid < 4) {
    gl = aSrc + (size_t)(wid * 64 + (lane >> 2)) * 256 + srcSlot;
    ldsOff = wid * 4096; nq = 4;
  } else {
    gl = bSrc + (size_t)((wid - 4) * 32 + (lane >> 2)) * 256 + srcSlot;
    ldsOff = 16384 + (wid - 4) * 2048; nq = 2;
  }

#define STAGE(buf, kb) do { \
    char* ldst = sm.bufs[buf] + ldsOff; \
    const char* gsp = gl + (kb) * 64; \
    _Pragma("unroll") for (int qq = 0; qq < 4; ++qq) \
      if (qq < nq) GLD16(ldst + qq * 1024, gsp + (size_t)qq * 4096); \
  } while (0)

  const int wr = wid >> 1, wc = wid & 1;   // wave: 64t x 64j
  const int l15 = lane & 15, h = lane >> 4;
  // per-ks read offsets: 16B slot g = ks*2 + (h>>1) (swizzled), low half by h&1
  const int swz = (l15 >> 1) & 3;
  const int hlo = (h & 1) * 8;
  const int sx0 = ((((h >> 1)) ^ swz) << 4) + hlo;
  const int sx1 = (((2 + (h >> 1)) ^ swz) << 4) + hlo;

  f32x4 acc[4][4];
#pragma unroll
  for (int fa = 0; fa < 4; ++fa)
#pragma unroll
    for (int fb = 0; fb < 4; ++fb) acc[fa][fb] = (f32x4){0.f, 0.f, 0.f, 0.f};

  // loop-invariant LDS read bases
  const char* aptr = sm.bufs[0] + (wr * 64 + l15) * 64;
  const char* bptr = sm.bufs[0] + 16384 + (wc * 64 + l15) * 64;

  STAGE(0, 0);
  __syncthreads();
#pragma unroll
  for (int kb = 0; kb < 4; ++kb) {   // K = 256 = 4 * 64
    const int bo = (kb & 1) * 24576;
    if (kb < 3) STAGE((kb & 1) ^ 1, kb + 1);   // issue next-tile loads before compute
#pragma unroll
    for (int ks = 0; ks < 2; ++ks) {           // two K=32 MFMA steps per kb
      const int sx = ks ? sx1 : sx0;
      long af[4], bg[4];
#pragma unroll
      for (int fa = 0; fa < 4; ++fa)
        af[fa] = *(const long*)(aptr + bo + fa * 1024 + sx);
#pragma unroll
      for (int fb = 0; fb < 4; ++fb)
        bg[fb] = *(const long*)(bptr + bo + fb * 1024 + sx);
#pragma unroll
      for (int fa = 0; fa < 4; ++fa)
#pragma unroll
        for (int fb = 0; fb < 4; ++fb)
          acc[fa][fb] = __builtin_amdgcn_mfma_f32_16x16x32_fp8_fp8(af[fa], bg[fb], acc[fa][fb], 0, 0, 0);
    }
    __syncthreads();
  }

  // ---- epilogue: packed-key dual argmax (u32: [31:13]=bits(acc+512), [12:0]=8191-t) ----
  const float rf = (float)relax[0];
  float jx[4], jy[4];
#pragma unroll
  for (int fb = 0; fb < 4; ++fb) {
    const int jl = wc * 64 + fb * 16 + l15;
    jx[fb] = sm.jc[jl]; jy[fb] = sm.jc[128 + jl];
  }
  unsigned int kA[4] = {0u, 0u, 0u, 0u}, kI[4] = {0u, 0u, 0u, 0u};
  const unsigned int tinv0 = (unsigned int)(8191 - tbase);

#define EPILOG(TAIL) \
  _Pragma("unroll") for (int fa = 0; fa < 4; ++fa) { \
    _Pragma("unroll") for (int i = 0; i < 4; ++i) { \
      const int tl = wr * 64 + fa * 16 + h * 4 + i; \
      const float tx = sm.tc[tl], ty = sm.tc[256 + tl]; \
      const unsigned int tinv = tinv0 - tl; \
      _Pragma("unroll") for (int fb = 0; fb < 4; ++fb) { \
        unsigned int key = (__float_as_uint(acc[fa][fb][i] + 512.f) & 0xFFFFE000u) | tinv; \
        if (TAIL && (tbase + tl >= NP)) key = 0u; \
        if (key > kA[fb]) kA[fb] = key; \
        const float mm = fmaxf(fabsf(tx - jx[fb]), fabsf(ty - jy[fb])); \
        const unsigned int keyI = (mm <= rf) ? 0u : key; \
        if (keyI > kI[fb]) kI[fb] = keyI; \
      } \
    } \
  }

  if (tbase + BT <= NP) { EPILOG(false) } else { EPILOG(true) }
#undef EPILOG

  // reduce over the 4 h-groups (disjoint t subsets, same j); red aliases bufs[0]
  uint2* red = (uint2*)sm.bufs[0];   // [4][128]; safe: last K-step barrier passed
#pragma unroll
  for (int fb = 0; fb < 4; ++fb) {
#pragma unroll
    for (int d = 16; d < 64; d <<= 1) {
      const unsigned int oA = __shfl_xor(kA[fb], d);
      const unsigned int oI = __shfl_xor(kI[fb], d);
      if (oA > kA[fb]) kA[fb] = oA;
      if (oI > kI[fb]) kI[fb] = oI;
    }
    if (h == 0) red[wr * 128 + wc * 64 + fb * 16 + l15] = make_uint2(kA[fb], kI[fb]);
  }
  __syncthreads();
  if (tid < 128) {
    const int jg = jbase + tid;
    if (jg < NP) {
      unsigned int a = red[tid].x, c = red[tid].y;
#pragma unroll
      for (int g = 1; g < 4; ++g) {
        if (red[g * 128 + tid].x > a) a = red[g * 128 + tid].x;
        if (red[g * 128 + tid].y > c) c = red[g * 128 + tid].y;
      }
      partial[((size_t)b * NP + jg) * NTT + tt] = make_uint2(a, c);
    }
  }
#undef STAGE
}

// ---------------- fused combine + per-point loss + recall (wave per point) ----------------
__global__ __launch_bounds__(256)
void k_loss(const unsigned short* __restrict__ refB, const unsigned short* __restrict__ tarB,
            const float* __restrict__ un, const uint2* __restrict__ partial,
            float* __restrict__ loss_arr, float* __restrict__ rec_arr) {
  const int w = threadIdx.x >> 6, lane = threadIdx.x & 63;
  const int n = blockIdx.x * 4 + w;
  const int b = blockIdx.y;
  const int bn = b * NP + n;
  unsigned int kA = 0u, kI = 0u;
  if (lane < NTT) {
    const uint2 p = partial[(size_t)bn * NTT + lane];
    kA = p.x; kI = p.y;
  }
#pragma unroll
  for (int d = 1; d < 64; d <<= 1) {
    const unsigned int oA = __shfl_xor(kA, d);
    const unsigned int oI = __shfl_xor(kI, d);
    if (oA > kA) kA = oA;
    if (oI > kI) kI = oI;
  }
  const int nn  = 8191 - (int)(kA & 0x1FFFu);
  const int neg = 8191 - (int)(kI & 0x1FFFu);
  const ushort4 rv = *(const ushort4*)(refB + ((size_t)b * NPAD + n) * CDIM + lane * 4);
  const ushort4 tv = *(const ushort4*)(tarB + ((size_t)b * NPAD + n) * CDIM + lane * 4);
  const ushort4 gv = *(const ushort4*)(tarB + ((size_t)b * NPAD + neg) * CDIM + lane * 4);
  float dp = 0.f, dn = 0.f, d;
  d = bf2f(rv.x) - bf2f(tv.x) + 1e-6f; dp += d * d;
  d = bf2f(rv.y) - bf2f(tv.y) + 1e-6f; dp += d * d;
  d = bf2f(rv.z) - bf2f(tv.z) + 1e-6f; dp += d * d;
  d = bf2f(rv.w) - bf2f(tv.w) + 1e-6f; dp += d * d;
  d = bf2f(rv.x) - bf2f(gv.x) + 1e-6f; dn += d * d;
  d = bf2f(rv.y) - bf2f(gv.y) + 1e-6f; dn += d * d;
  d = bf2f(rv.z) - bf2f(gv.z) + 1e-6f; dn += d * d;
  d = bf2f(rv.w) - bf2f(gv.w) + 1e-6f; dn += d * d;
#pragma unroll
  for (int off = 1; off < 64; off <<= 1) {
    dp += __shfl_xor(dp, off);
    dn += __shfl_xor(dn, off);
  }
  if (lane == 0) {
    const float loss = fmaxf(sqrtf(dp) - sqrtf(dn) + 0.2f, 0.f);
    const float* unb = un + (size_t)b * 2 * NP;
    const float rec = (unb[nn] == unb[n] && unb[NP + nn] == unb[NP + n]) ? 1.f : 0.f;
    loss_arr[bn] = loss;
    rec_arr[bn] = rec;
  }
}

// ---------------- final deterministic reduce ----------------
__global__ __launch_bounds__(256)
void k_finalize(const float* __restrict__ loss_arr, const float* __restrict__ rec_arr,
                float* __restrict__ out) {
  __shared__ float l[256], rr[256];
  float ls = 0.f, rs = 0.f;
  for (int i = threadIdx.x; i < BQ * NP; i += 256) { ls += loss_arr[i]; rs += rec_arr[i]; }
  l[threadIdx.x] = ls;
  rr[threadIdx.x] = rs;
  __syncthreads();
  for (int s = 128; s > 0; s >>= 1) {
    if (threadIdx.x < s) { l[threadIdx.x] += l[threadIdx.x + s]; rr[threadIdx.x] += rr[threadIdx.x + s]; }
    __syncthreads();
  }
  if (threadIdx.x == 0) {
    out[0] = l[0] / (float)(BQ * NP);
    out[1] = rr[0] / (float)(BQ * NP);
  }
}

extern "C" void kernel_launch(void* const* d_in, const int* in_sizes, int n_in,
                              void* d_out, int out_size, void* d_ws, size_t ws_size,
                              hipStream_t stream) {
  const float* src  = (const float*)d_in[0];
  const float* tgt  = (const float*)d_in[1];
  const float* spts = (const float*)d_in[2];
  const float* tpts = (const float*)d_in[3];
  const float* un   = (const float*)d_in[4];
  const int* relax  = (const int*)d_in[5];

  char* ws = (char*)d_ws;
  unsigned short* desT     = (unsigned short*)(ws + WS_DEST);
  uint2*          partial  = (uint2*)(ws + WS_PART);   // aliases desT (dead by then)
  unsigned short* refB     = (unsigned short*)(ws + WS_REFB);
  unsigned short* tarB     = (unsigned short*)(ws + WS_TARB);
  unsigned char*  refQ     = (unsigned char*)(ws + WS_REFQ);
  unsigned char*  tarQ     = (unsigned char*)(ws + WS_TARQ);
  float*          loss_arr = (float*)(ws + WS_LOSS);
  float*          rec_arr  = (float*)(ws + WS_REC);
  float*          out      = (float*)d_out;

  k_transpose<<<dim3(NP / 32, CDIM / 64, 8), dim3(32, 8), 0, stream>>>(src, tgt, desT);
  k_sample<<<dim3(NPAD / 4, BQ, 2), 256, 0, stream>>>(desT, spts, tpts, refB, tarB, refQ, tarQ);
  k_mfma_argmax<<<NBLK, 512, 0, stream>>>(tarQ, refQ, un, relax, partial);
  k_loss<<<dim3(NP / 4, BQ), 256, 0, stream>>>(refB, tarB, un, partial, loss_arr, rec_arr);
  k_finalize<<<1, 256, 0, stream>>>(loss_arr, rec_arr, out);
}

// Round 9
// 114.347 us; speedup vs baseline: 4.7400x; 1.0460x over previous
//
#include <hip/hip_runtime.h>
#include <cstdint>
#include <cstddef>

// Problem constants: B=4, C=256, H=60, W=80, N=4800
#define BQ 4
#define CDIM 256
#define HH 60
#define WW 80
#define NP 4800
#define NPAD 4864          // lcm pad: 38*128 = 19*256
#define BT 256             // tile rows (t, A = tar)
#define BJ 128             // tile cols (j, B = ref)
#define NTT 19             // t tiles (256)
#define NTJ 38             // j tiles (128)
#define NBLK (BQ * NTJ * NTT)   // 2888, %8==0

typedef float f32x4 __attribute__((ext_vector_type(4)));
typedef unsigned short u16x8 __attribute__((ext_vector_type(8)));
typedef long longx2 __attribute__((ext_vector_type(2)));

// ---------------- ws layout (bytes) ----------------
#define WS_DEST 0              // bf16 2*4*4800*256*2 = 19,660,800 (dead after k_sample)
#define WS_PART 0              // uint2 4*4800*19*8 = 2,918,400 (aliases desT)
#define WS_REFB 19660800       // bf16 4*4864*256*2 = 9,961,472 (for k_loss)
#define WS_TARB 29622272       // bf16                9,961,472
#define WS_REFQ 39583744       // fp8 4*4864*256 = 4,980,736 (for GEMM, k-permuted)
#define WS_TARQ 44564480       // fp8                4,980,736
#define WS_LOSS 49545216       // f32 19200 = 76,800
#define WS_REC  49622016       // f32 19200
// end 49,698,816

#define GLD16(dst, src) __builtin_amdgcn_global_load_lds( \
    (const __attribute__((address_space(1))) void*)(src), \
    (__attribute__((address_space(3))) void*)(dst), 16, 0, 0)

__device__ inline unsigned short f2bf(float f) {
  unsigned int u = __float_as_uint(f);
  return (unsigned short)((u + 0x7FFFu + ((u >> 16) & 1u)) >> 16);  // RNE
}
__device__ inline float bf2f(unsigned short s) {
  return __uint_as_float((unsigned int)s << 16);
}
// f32 -> OCP e4m3fn, RNE, clamp to +-448, subnormals handled
__device__ inline unsigned char f2e4m3(float x) {
  float ax = fminf(fabsf(x), 448.f);
  const unsigned int sign = (__float_as_uint(x) >> 24) & 0x80u;
  if (ax < 0.015625f) {                     // below 2^-6: subnormal (or carry to 0x08)
    const int M = (int)rintf(ax * 512.f);   // 0..8; 8 == 2^-6 encodes as E=1,M=0
    return (unsigned char)(sign | (unsigned int)M);
  }
  unsigned int u = __float_as_uint(ax);
  u += 0x7FFFFu + ((u >> 20) & 1u);         // RNE at mantissa bit 20 (carry ok)
  unsigned int e = (u >> 23) - 120u;        // exp bias 127 -> 7
  unsigned int m = (u >> 20) & 7u;
  if (e >= 16u) { e = 15u; m = 6u; }        // clamp to 448 (rounding overshoot)
  return (unsigned char)(sign | (e << 3) | m);
}

// ---------------- transpose des (C, HW) f32 -> (HW, C) bf16 ----------------
__global__ __launch_bounds__(256)
void k_transpose(const float* __restrict__ src, const float* __restrict__ tgt,
                 unsigned short* __restrict__ desT) {
  __shared__ float tile[64][33];
  const int z = blockIdx.z;  // tensor*4 + b
  const float* in = ((z >> 2) ? tgt : src) + (size_t)(z & 3) * CDIM * NP;
  unsigned short* out = desT + (size_t)z * NP * CDIM;
  const int hw0 = blockIdx.x * 32;
  const int c0 = blockIdx.y * 64;
  const int tx = threadIdx.x, ty = threadIdx.y;
#pragma unroll
  for (int q = 0; q < 8; ++q)
    tile[ty + q * 8][tx] = in[(size_t)(c0 + ty + q * 8) * NP + hw0 + tx];
  __syncthreads();
  const int lt = ty * 32 + tx;
  const int c2 = lt & 7;        // 8 channels each
  const int hw = lt >> 3;       // 0..31
  u16x8 o;
#pragma unroll
  for (int k = 0; k < 8; ++k) o[k] = f2bf(tile[c2 * 8 + k][hw]);
  *(u16x8*)(out + (size_t)(hw0 + hw) * CDIM + c0 + c2 * 8) = o;
}

// ---------------- bilinear sample + L2 normalize -> bf16 rows + k-permuted fp8 rows ----------------
// fp8 rows store byte (kb*64 + ks*32 + h*8 + b) at position (kb*64 + h*16 + ks*8 + b):
// a single ds_read_b128 at slot h then yields both K=32 MFMA slices (low/high 8 B).
// Same permutation on ref and tar -> dot products unchanged.
__global__ __launch_bounds__(256)
void k_sample(const unsigned short* __restrict__ desT,
              const float* __restrict__ spts, const float* __restrict__ tpts,
              unsigned short* __restrict__ refB, unsigned short* __restrict__ tarB,
              unsigned char* __restrict__ refQ, unsigned char* __restrict__ tarQ) {
  const int w = threadIdx.x >> 6, lane = threadIdx.x & 63;
  const int n = blockIdx.x * 4 + w;         // 0..NPAD-1
  const int b = blockIdx.y;
  const int tensor = blockIdx.z;            // 0: ref, 1: tar
  unsigned short* outRowB = (tensor ? tarB : refB) + ((size_t)b * NPAD + n) * CDIM;
  unsigned char*  outRowQ = (tensor ? tarQ : refQ) + ((size_t)b * NPAD + n) * CDIM;
  const int c0 = lane * 4;
  // permuted uchar4 position (bits: kb[7:6] | h[4:3]->[5:4] | ks[5]->[3] | b[2:0])
  const int dstq = (c0 & 0xC0) | ((c0 & 24) << 1) | ((c0 & 32) >> 2) | (c0 & 7);
  if (n >= NP) {  // zero pad rows (uniform per wave)
    *(ushort4*)(outRowB + c0) = make_ushort4(0, 0, 0, 0);
    *(uchar4*)(outRowQ + dstq) = make_uchar4(0, 0, 0, 0);
    return;
  }
  const float* pts = (tensor ? tpts : spts) + ((size_t)b * NP + n) * 2;
  const float gx = pts[0], gy = pts[1];
  const float x = (gx + 1.f) * ((WW - 1) * 0.5f);
  const float y = (gy + 1.f) * ((HH - 1) * 0.5f);
  float x0f = fminf(fmaxf(floorf(x), 0.f), (float)(WW - 1));
  float y0f = fminf(fmaxf(floorf(y), 0.f), (float)(HH - 1));
  float x1f = fminf(x0f + 1.f, (float)(WW - 1));
  float y1f = fminf(y0f + 1.f, (float)(HH - 1));
  const float wx = x - x0f, wy = y - y0f;
  const int ix0 = (int)x0f, ix1 = (int)x1f, iy0 = (int)y0f, iy1 = (int)y1f;
  const unsigned short* base = desT + (size_t)(tensor * 4 + b) * NP * CDIM + c0;
  const ushort4 u00 = *(const ushort4*)(base + (size_t)(iy0 * WW + ix0) * CDIM);
  const ushort4 u01 = *(const ushort4*)(base + (size_t)(iy0 * WW + ix1) * CDIM);
  const ushort4 u10 = *(const ushort4*)(base + (size_t)(iy1 * WW + ix0) * CDIM);
  const ushort4 u11 = *(const ushort4*)(base + (size_t)(iy1 * WW + ix1) * CDIM);
  const float w00 = (1.f - wx) * (1.f - wy), w01 = wx * (1.f - wy);
  const float w10 = (1.f - wx) * wy,         w11 = wx * wy;
  float4 v;
  v.x = bf2f(u00.x) * w00 + bf2f(u01.x) * w01 + bf2f(u10.x) * w10 + bf2f(u11.x) * w11;
  v.y = bf2f(u00.y) * w00 + bf2f(u01.y) * w01 + bf2f(u10.y) * w10 + bf2f(u11.y) * w11;
  v.z = bf2f(u00.z) * w00 + bf2f(u01.z) * w01 + bf2f(u10.z) * w10 + bf2f(u11.z) * w11;
  v.w = bf2f(u00.w) * w00 + bf2f(u01.w) * w01 + bf2f(u10.w) * w10 + bf2f(u11.w) * w11;
  float s0 = v.x + 1e-8f, s1 = v.y + 1e-8f, s2 = v.z + 1e-8f, s3 = v.w + 1e-8f;
  float sum = s0 * s0 + s1 * s1 + s2 * s2 + s3 * s3;
#pragma unroll
  for (int d = 1; d < 64; d <<= 1) sum += __shfl_xor(sum, d);
  const float inv = 1.f / (sqrtf(sum) + 1e-8f);
  *(ushort4*)(outRowB + c0) =
      make_ushort4(f2bf(v.x * inv), f2bf(v.y * inv), f2bf(v.z * inv), f2bf(v.w * inv));
  const float invq = inv * 16.f;   // scale into e4m3 normal range; dot' = 256*dot
  *(uchar4*)(outRowQ + dstq) =
      make_uchar4(f2e4m3(v.x * invq), f2e4m3(v.y * invq), f2e4m3(v.z * invq), f2e4m3(v.w * invq));
}

// ---------------- fp8 MFMA GEMM (256t x 128j, BK=64) + fused dual argmax ----------------
// LDS rows 64 B, 4 slots of 16 B; store slot s holds global slot s^((row>>1)&3) (round-5
// proven zero-conflict b128 pattern). One ds_read_b128 per fragment per kb covers both
// K=32 MFMA steps (k-permuted rows). red[] aliases bufs[0] after the last k-loop barrier.
// launch_bounds (512,4): 2 blocks/CU. (512,6) spilled acc -> 7x regression (round-6 lesson).
struct Smem {
  char bufs[2][24576];   // per buf: A [256][64B] @0, B [128][64B] @16384
  float2 tc2[256];       // t coords (x,y)
  float2 jc2[128];       // j coords (x,y)
};                       // 52,224 B

__global__ __launch_bounds__(512, 4)
void k_mfma_argmax(const unsigned char* __restrict__ tarQ,
                   const unsigned char* __restrict__ refQ,
                   const float* __restrict__ un, const int* __restrict__ relax,
                   uint2* __restrict__ partial) {
  __shared__ Smem sm;
  const int tid = threadIdx.x;
  const int lane = tid & 63;
  const int wid = tid >> 6;

  // XCD swizzle (2888 % 8 == 0)
  const int bid = blockIdx.x;
  const int item = (bid & 7) * (NBLK / 8) + (bid >> 3);
  const int b = item / (NTJ * NTT);
  const int r2 = item - b * (NTJ * NTT);
  const int jt = r2 / NTT, tt = r2 % NTT;
  const int tbase = tt * BT, jbase = jt * BJ;
  const float* unb = un + (size_t)b * 2 * NP;

  // stage coords into LDS (before first barrier)
  if (tid < 256) {
    const int tg = (tbase + tid < NP) ? tbase + tid : NP - 1;
    sm.tc2[tid] = make_float2(unb[tg], unb[NP + tg]);
  } else if (tid < 384) {
    const int i2 = tid - 256;
    const int jg = (jbase + i2 < NP) ? jbase + i2 : NP - 1;
    sm.jc2[i2] = make_float2(unb[jg], unb[NP + jg]);
  }

  // staging: waves 0-3 -> A (64 rows each), waves 4-7 -> B (32 rows each)
  // global rows are 256 B (fp8, k-permuted); kb selects a 64-B slice. Source slot pre-swizzled.
  const char* aSrc = (const char*)(tarQ + ((size_t)b * NPAD + tbase) * CDIM);
  const char* bSrc = (const char*)(refQ + ((size_t)b * NPAD + jbase) * CDIM);
  const int srcSlot = ((lane & 3) ^ ((lane >> 3) & 3)) * 16;
  const char* gl; int ldsOff, nq;
  if (wid < 4) {
    gl = aSrc + (size_t)(wid * 64 + (lane >> 2)) * 256 + srcSlot;
    ldsOff = wid * 4096; nq = 4;
  } else {
    gl = bSrc + (size_t)((wid - 4) * 32 + (lane >> 2)) * 256 + srcSlot;
    ldsOff = 16384 + (wid - 4) * 2048; nq = 2;
  }

#define STAGE(buf, kb) do { \
    char* ldst = sm.bufs[buf] + ldsOff; \
    const char* gsp = gl + (kb) * 64; \
    _Pragma("unroll") for (int qq = 0; qq < 4; ++qq) \
      if (qq < nq) GLD16(ldst + qq * 1024, gsp + (size_t)qq * 4096); \
  } while (0)

  const int wr = wid >> 1, wc = wid & 1;   // wave: 64t x 64j
  const int l15 = lane & 15, h = lane >> 4;
  const int sx = (h ^ ((l15 >> 1) & 3)) << 4;   // swizzled 16-B slot (round-5 pattern)

  f32x4 acc[4][4];
#pragma unroll
  for (int fa = 0; fa < 4; ++fa)
#pragma unroll
    for (int fb = 0; fb < 4; ++fb) acc[fa][fb] = (f32x4){0.f, 0.f, 0.f, 0.f};

  // loop-invariant LDS read bases: fragment reads are base + imm offset
  const char* aptr = sm.bufs[0] + (wr * 64 + l15) * 64 + sx;
  const char* bptr = sm.bufs[0] + 16384 + (wc * 64 + l15) * 64 + sx;

  STAGE(0, 0);
  __syncthreads();
#pragma unroll
  for (int kb = 0; kb < 4; ++kb) {   // K = 256 = 4 * 64
    const int bo = (kb & 1) * 24576;
    if (kb < 3) STAGE((kb & 1) ^ 1, kb + 1);   // issue next-tile loads before compute
    longx2 af[4], bg[4];                        // one b128 = both K=32 slices
#pragma unroll
    for (int fa = 0; fa < 4; ++fa)
      af[fa] = *(const longx2*)(aptr + bo + fa * 1024);
#pragma unroll
    for (int fb = 0; fb < 4; ++fb)
      bg[fb] = *(const longx2*)(bptr + bo + fb * 1024);
#pragma unroll
    for (int fa = 0; fa < 4; ++fa)
#pragma unroll
      for (int fb = 0; fb < 4; ++fb)
        acc[fa][fb] = __builtin_amdgcn_mfma_f32_16x16x32_fp8_fp8(af[fa].x, bg[fb].x, acc[fa][fb], 0, 0, 0);
#pragma unroll
    for (int fa = 0; fa < 4; ++fa)
#pragma unroll
      for (int fb = 0; fb < 4; ++fb)
        acc[fa][fb] = __builtin_amdgcn_mfma_f32_16x16x32_fp8_fp8(af[fa].y, bg[fb].y, acc[fa][fb], 0, 0, 0);
    __syncthreads();
  }

  // ---- epilogue: packed-key dual argmax (u32: [31:13]=bits(acc+512), [12:0]=8191-t) ----
  const float rf = (float)relax[0];
  float jx[4], jy[4];
#pragma unroll
  for (int fb = 0; fb < 4; ++fb) {
    const float2 jj = sm.jc2[wc * 64 + fb * 16 + l15];
    jx[fb] = jj.x; jy[fb] = jj.y;
  }
  unsigned int kA[4] = {0u, 0u, 0u, 0u}, kI[4] = {0u, 0u, 0u, 0u};
  const unsigned int tinv0 = (unsigned int)(8191 - tbase);

#define EPILOG(TAIL) \
  _Pragma("unroll") for (int fa = 0; fa < 4; ++fa) { \
    _Pragma("unroll") for (int i = 0; i < 4; ++i) { \
      const int tl = wr * 64 + fa * 16 + h * 4 + i; \
      const float2 tj = sm.tc2[tl]; \
      const unsigned int tinv = tinv0 - tl; \
      _Pragma("unroll") for (int fb = 0; fb < 4; ++fb) { \
        unsigned int key = (__float_as_uint(acc[fa][fb][i] + 512.f) & 0xFFFFE000u) | tinv; \
        if (TAIL && (tbase + tl >= NP)) key = 0u; \
        if (key > kA[fb]) kA[fb] = key; \
        const float mm = fmaxf(fabsf(tj.x - jx[fb]), fabsf(tj.y - jy[fb])); \
        const unsigned int keyI = (mm <= rf) ? 0u : key; \
        if (keyI > kI[fb]) kI[fb] = keyI; \
      } \
    } \
  }

  if (tbase + BT <= NP) { EPILOG(false) } else { EPILOG(true) }
#undef EPILOG

  // reduce over the 4 h-groups (disjoint t subsets, same j); red aliases bufs[0]
  uint2* red = (uint2*)sm.bufs[0];   // [4][128]; safe: last K-step barrier passed
#pragma unroll
  for (int fb = 0; fb < 4; ++fb) {
#pragma unroll
    for (int d = 16; d < 64; d <<= 1) {
      const unsigned int oA = __shfl_xor(kA[fb], d);
      const unsigned int oI = __shfl_xor(kI[fb], d);
      if (oA > kA[fb]) kA[fb] = oA;
      if (oI > kI[fb]) kI[fb] = oI;
    }
    if (h == 0) red[wr * 128 + wc * 64 + fb * 16 + l15] = make_uint2(kA[fb], kI[fb]);
  }
  __syncthreads();
  if (tid < 128) {
    const int jg = jbase + tid;
    if (jg < NP) {
      unsigned int a = red[tid].x, c = red[tid].y;
#pragma unroll
      for (int g = 1; g < 4; ++g) {
        if (red[g * 128 + tid].x > a) a = red[g * 128 + tid].x;
        if (red[g * 128 + tid].y > c) c = red[g * 128 + tid].y;
      }
      partial[((size_t)b * NP + jg) * NTT + tt] = make_uint2(a, c);
    }
  }
#undef STAGE
}

// ---------------- fused combine + per-point loss + recall (wave per point) ----------------
__global__ __launch_bounds__(256)
void k_loss(const unsigned short* __restrict__ refB, const unsigned short* __restrict__ tarB,
            const float* __restrict__ un, const uint2* __restrict__ partial,
            float* __restrict__ loss_arr, float* __restrict__ rec_arr) {
  const int w = threadIdx.x >> 6, lane = threadIdx.x & 63;
  const int n = blockIdx.x * 4 + w;
  const int b = blockIdx.y;
  const int bn = b * NP + n;
  unsigned int kA = 0u, kI = 0u;
  if (lane < NTT) {
    const uint2 p = partial[(size_t)bn * NTT + lane];
    kA = p.x; kI = p.y;
  }
#pragma unroll
  for (int d = 1; d < 64; d <<= 1) {
    const unsigned int oA = __shfl_xor(kA, d);
    const unsigned int oI = __shfl_xor(kI, d);
    if (oA > kA) kA = oA;
    if (oI > kI) kI = oI;
  }
  const int nn  = 8191 - (int)(kA & 0x1FFFu);
  const int neg = 8191 - (int)(kI & 0x1FFFu);
  const ushort4 rv = *(const ushort4*)(refB + ((size_t)b * NPAD + n) * CDIM + lane * 4);
  const ushort4 tv = *(const ushort4*)(tarB + ((size_t)b * NPAD + n) * CDIM + lane * 4);
  const ushort4 gv = *(const ushort4*)(tarB + ((size_t)b * NPAD + neg) * CDIM + lane * 4);
  float dp = 0.f, dn = 0.f, d;
  d = bf2f(rv.x) - bf2f(tv.x) + 1e-6f; dp += d * d;
  d = bf2f(rv.y) - bf2f(tv.y) + 1e-6f; dp += d * d;
  d = bf2f(rv.z) - bf2f(tv.z) + 1e-6f; dp += d * d;
  d = bf2f(rv.w) - bf2f(tv.w) + 1e-6f; dp += d * d;
  d = bf2f(rv.x) - bf2f(gv.x) + 1e-6f; dn += d * d;
  d = bf2f(rv.y) - bf2f(gv.y) + 1e-6f; dn += d * d;
  d = bf2f(rv.z) - bf2f(gv.z) + 1e-6f; dn += d * d;
  d = bf2f(rv.w) - bf2f(gv.w) + 1e-6f; dn += d * d;
#pragma unroll
  for (int off = 1; off < 64; off <<= 1) {
    dp += __shfl_xor(dp, off);
    dn += __shfl_xor(dn, off);
  }
  if (lane == 0) {
    const float loss = fmaxf(sqrtf(dp) - sqrtf(dn) + 0.2f, 0.f);
    const float* unb = un + (size_t)b * 2 * NP;
    const float rec = (unb[nn] == unb[n] && unb[NP + nn] == unb[NP + n]) ? 1.f : 0.f;
    loss_arr[bn] = loss;
    rec_arr[bn] = rec;
  }
}

// ---------------- final deterministic reduce ----------------
__global__ __launch_bounds__(256)
void k_finalize(const float* __restrict__ loss_arr, const float* __restrict__ rec_arr,
                float* __restrict__ out) {
  __shared__ float l[256], rr[256];
  float ls = 0.f, rs = 0.f;
  for (int i = threadIdx.x; i < BQ * NP; i += 256) { ls += loss_arr[i]; rs += rec_arr[i]; }
  l[threadIdx.x] = ls;
  rr[threadIdx.x] = rs;
  __syncthreads();
  for (int s = 128; s > 0; s >>= 1) {
    if (threadIdx.x < s) { l[threadIdx.x] += l[threadIdx.x + s]; rr[threadIdx.x] += rr[threadIdx.x + s]; }
    __syncthreads();
  }
  if (threadIdx.x == 0) {
    out[0] = l[0] / (float)(BQ * NP);
    out[1] = rr[0] / (float)(BQ * NP);
  }
}

extern "C" void kernel_launch(void* const* d_in, const int* in_sizes, int n_in,
                              void* d_out, int out_size, void* d_ws, size_t ws_size,
                              hipStream_t stream) {
  const float* src  = (const float*)d_in[0];
  const float* tgt  = (const float*)d_in[1];
  const float* spts = (const float*)d_in[2];
  const float* tpts = (const float*)d_in[3];
  const float* un   = (const float*)d_in[4];
  const int* relax  = (const int*)d_in[5];

  char* ws = (char*)d_ws;
  unsigned short* desT     = (unsigned short*)(ws + WS_DEST);
  uint2*          partial  = (uint2*)(ws + WS_PART);   // aliases desT (dead by then)
  unsigned short* refB     = (unsigned short*)(ws + WS_REFB);
  unsigned short* tarB     = (unsigned short*)(ws + WS_TARB);
  unsigned char*  refQ     = (unsigned char*)(ws + WS_REFQ);
  unsigned char*  tarQ     = (unsigned char*)(ws + WS_TARQ);
  float*          loss_arr = (float*)(ws + WS_LOSS);
  float*          rec_arr  = (float*)(ws + WS_REC);
  float*          out      = (float*)d_out;

  k_transpose<<<dim3(NP / 32, CDIM / 64, 8), dim3(32, 8), 0, stream>>>(src, tgt, desT);
  k_sample<<<dim3(NPAD / 4, BQ, 2), 256, 0, stream>>>(desT, spts, tpts, refB, tarB, refQ, tarQ);
  k_mfma_argmax<<<NBLK, 512, 0, stream>>>(tarQ, refQ, un, relax, partial);
  k_loss<<<dim3(NP / 4, BQ), 256, 0, stream>>>(refB, tarB, un, partial, loss_arr, rec_arr);
  k_finalize<<<1, 256, 0, stream>>>(loss_arr, rec_arr, out);
}

// Round 10
// 107.431 us; speedup vs baseline: 5.0451x; 1.0644x over previous
//
#include <hip/hip_runtime.h>
#include <cstdint>
#include <cstddef>

// Problem constants: B=4, C=256, H=60, W=80, N=4800
#define BQ 4
#define CDIM 256
#define HH 60
#define WW 80
#define NP 4800
#define NPAD 4864          // 38*128
#define BT 128             // tile rows (t, A = tar)
#define BJ 128             // tile cols (j, B = ref)
#define NTT 38             // t tiles (128)
#define NTJ 38             // j tiles (128)
#define NBLK (BQ * NTJ * NTT)   // 5776, %8==0

typedef float f32x4 __attribute__((ext_vector_type(4)));
typedef unsigned short u16x8 __attribute__((ext_vector_type(8)));
typedef long longx2 __attribute__((ext_vector_type(2)));

// ---------------- ws layout (bytes) ----------------
#define WS_DEST 0              // bf16 2*4*4800*256*2 = 19,660,800 (dead after k_sample)
#define WS_PART 0              // uint2 4*4800*38*8 = 5,836,800 (aliases desT)
#define WS_REFB 19660800       // bf16 4*4864*256*2 = 9,961,472 (for k_loss)
#define WS_TARB 29622272       // bf16                9,961,472
#define WS_REFQ 39583744       // fp8 4*4864*256 = 4,980,736 (for GEMM, k-permuted)
#define WS_TARQ 44564480       // fp8                4,980,736
#define WS_LOSS 49545216       // f32 19200 = 76,800
#define WS_REC  49622016       // f32 19200
// end 49,698,816

#define GLD16(dst, src) __builtin_amdgcn_global_load_lds( \
    (const __attribute__((address_space(1))) void*)(src), \
    (__attribute__((address_space(3))) void*)(dst), 16, 0, 0)

__device__ inline unsigned short f2bf(float f) {
  unsigned int u = __float_as_uint(f);
  return (unsigned short)((u + 0x7FFFu + ((u >> 16) & 1u)) >> 16);  // RNE
}
__device__ inline float bf2f(unsigned short s) {
  return __uint_as_float((unsigned int)s << 16);
}
// f32 -> OCP e4m3fn, RNE, clamp to +-448, subnormals handled
__device__ inline unsigned char f2e4m3(float x) {
  float ax = fminf(fabsf(x), 448.f);
  const unsigned int sign = (__float_as_uint(x) >> 24) & 0x80u;
  if (ax < 0.015625f) {                     // below 2^-6: subnormal (or carry to 0x08)
    const int M = (int)rintf(ax * 512.f);   // 0..8; 8 == 2^-6 encodes as E=1,M=0
    return (unsigned char)(sign | (unsigned int)M);
  }
  unsigned int u = __float_as_uint(ax);
  u += 0x7FFFFu + ((u >> 20) & 1u);         // RNE at mantissa bit 20 (carry ok)
  unsigned int e = (u >> 23) - 120u;        // exp bias 127 -> 7
  unsigned int m = (u >> 20) & 7u;
  if (e >= 16u) { e = 15u; m = 6u; }        // clamp to 448 (rounding overshoot)
  return (unsigned char)(sign | (e << 3) | m);
}

// ---------------- transpose des (C, HW) f32 -> (HW, C) bf16 ----------------
__global__ __launch_bounds__(256)
void k_transpose(const float* __restrict__ src, const float* __restrict__ tgt,
                 unsigned short* __restrict__ desT) {
  __shared__ float tile[64][33];
  const int z = blockIdx.z;  // tensor*4 + b
  const float* in = ((z >> 2) ? tgt : src) + (size_t)(z & 3) * CDIM * NP;
  unsigned short* out = desT + (size_t)z * NP * CDIM;
  const int hw0 = blockIdx.x * 32;
  const int c0 = blockIdx.y * 64;
  const int tx = threadIdx.x, ty = threadIdx.y;
#pragma unroll
  for (int q = 0; q < 8; ++q)
    tile[ty + q * 8][tx] = in[(size_t)(c0 + ty + q * 8) * NP + hw0 + tx];
  __syncthreads();
  const int lt = ty * 32 + tx;
  const int c2 = lt & 7;        // 8 channels each
  const int hw = lt >> 3;       // 0..31
  u16x8 o;
#pragma unroll
  for (int k = 0; k < 8; ++k) o[k] = f2bf(tile[c2 * 8 + k][hw]);
  *(u16x8*)(out + (size_t)(hw0 + hw) * CDIM + c0 + c2 * 8) = o;
}

// ---------------- bilinear sample + L2 normalize -> bf16 rows + k-permuted fp8 rows ----------------
// fp8 rows store byte (kb*64 + ks*32 + h*8 + b) at position (kb*64 + h*16 + ks*8 + b):
// a single ds_read_b128 at slot h then yields both K=32 MFMA slices (low/high 8 B).
// Same permutation on ref and tar -> dot products unchanged.
__global__ __launch_bounds__(256)
void k_sample(const unsigned short* __restrict__ desT,
              const float* __restrict__ spts, const float* __restrict__ tpts,
              unsigned short* __restrict__ refB, unsigned short* __restrict__ tarB,
              unsigned char* __restrict__ refQ, unsigned char* __restrict__ tarQ) {
  const int w = threadIdx.x >> 6, lane = threadIdx.x & 63;
  const int n = blockIdx.x * 4 + w;         // 0..NPAD-1
  const int b = blockIdx.y;
  const int tensor = blockIdx.z;            // 0: ref, 1: tar
  unsigned short* outRowB = (tensor ? tarB : refB) + ((size_t)b * NPAD + n) * CDIM;
  unsigned char*  outRowQ = (tensor ? tarQ : refQ) + ((size_t)b * NPAD + n) * CDIM;
  const int c0 = lane * 4;
  // permuted uchar4 position (bits: kb[7:6] | h[4:3]->[5:4] | ks[5]->[3] | b[2:0])
  const int dstq = (c0 & 0xC0) | ((c0 & 24) << 1) | ((c0 & 32) >> 2) | (c0 & 7);
  if (n >= NP) {  // zero pad rows (uniform per wave)
    *(ushort4*)(outRowB + c0) = make_ushort4(0, 0, 0, 0);
    *(uchar4*)(outRowQ + dstq) = make_uchar4(0, 0, 0, 0);
    return;
  }
  const float* pts = (tensor ? tpts : spts) + ((size_t)b * NP + n) * 2;
  const float gx = pts[0], gy = pts[1];
  const float x = (gx + 1.f) * ((WW - 1) * 0.5f);
  const float y = (gy + 1.f) * ((HH - 1) * 0.5f);
  float x0f = fminf(fmaxf(floorf(x), 0.f), (float)(WW - 1));
  float y0f = fminf(fmaxf(floorf(y), 0.f), (float)(HH - 1));
  float x1f = fminf(x0f + 1.f, (float)(WW - 1));
  float y1f = fminf(y0f + 1.f, (float)(HH - 1));
  const float wx = x - x0f, wy = y - y0f;
  const int ix0 = (int)x0f, ix1 = (int)x1f, iy0 = (int)y0f, iy1 = (int)y1f;
  const unsigned short* base = desT + (size_t)(tensor * 4 + b) * NP * CDIM + c0;
  const ushort4 u00 = *(const ushort4*)(base + (size_t)(iy0 * WW + ix0) * CDIM);
  const ushort4 u01 = *(const ushort4*)(base + (size_t)(iy0 * WW + ix1) * CDIM);
  const ushort4 u10 = *(const ushort4*)(base + (size_t)(iy1 * WW + ix0) * CDIM);
  const ushort4 u11 = *(const ushort4*)(base + (size_t)(iy1 * WW + ix1) * CDIM);
  const float w00 = (1.f - wx) * (1.f - wy), w01 = wx * (1.f - wy);
  const float w10 = (1.f - wx) * wy,         w11 = wx * wy;
  float4 v;
  v.x = bf2f(u00.x) * w00 + bf2f(u01.x) * w01 + bf2f(u10.x) * w10 + bf2f(u11.x) * w11;
  v.y = bf2f(u00.y) * w00 + bf2f(u01.y) * w01 + bf2f(u10.y) * w10 + bf2f(u11.y) * w11;
  v.z = bf2f(u00.z) * w00 + bf2f(u01.z) * w01 + bf2f(u10.z) * w10 + bf2f(u11.z) * w11;
  v.w = bf2f(u00.w) * w00 + bf2f(u01.w) * w01 + bf2f(u10.w) * w10 + bf2f(u11.w) * w11;
  float s0 = v.x + 1e-8f, s1 = v.y + 1e-8f, s2 = v.z + 1e-8f, s3 = v.w + 1e-8f;
  float sum = s0 * s0 + s1 * s1 + s2 * s2 + s3 * s3;
#pragma unroll
  for (int d = 1; d < 64; d <<= 1) sum += __shfl_xor(sum, d);
  const float inv = 1.f / (sqrtf(sum) + 1e-8f);
  *(ushort4*)(outRowB + c0) =
      make_ushort4(f2bf(v.x * inv), f2bf(v.y * inv), f2bf(v.z * inv), f2bf(v.w * inv));
  const float invq = inv * 16.f;   // scale into e4m3 normal range; dot' = 256*dot
  *(uchar4*)(outRowQ + dstq) =
      make_uchar4(f2e4m3(v.x * invq), f2e4m3(v.y * invq), f2e4m3(v.z * invq), f2e4m3(v.w * invq));
}

// ---------------- fp8 MFMA GEMM (128t x 128j, BK=64) + fused dual argmax ----------------
// 256 threads (4 waves of 64t x 64j), 4 blocks/CU: independent barrier groups let one
// block's VALU epilogue overlap another's MFMA k-loop (round-9 wall was their serial sum).
// LDS rows 64 B, zero-conflict swizzle (store slot s^((row>>1)&3), round-5 proven).
// One ds_read_b128 per fragment per kb covers both K=32 slices (k-permuted fp8 rows).
// red[] aliases bufs[0] after its last reads (kb=2 barrier). VGPR cap 128 = current
// pressure (acc in AGPRs); (512,6)-style over-subscription spills — round-6 lesson.
struct Smem {
  char bufs[2][16384];   // per buf: A [128][64B] @0, B [128][64B] @8192
  float2 tc2[128];       // t coords (x,y)
  float2 jc2[128];       // j coords (x,y)
};                       // 34,816 B -> 4 blocks/CU

__global__ __launch_bounds__(256, 4)
void k_mfma_argmax(const unsigned char* __restrict__ tarQ,
                   const unsigned char* __restrict__ refQ,
                   const float* __restrict__ un, const int* __restrict__ relax,
                   uint2* __restrict__ partial) {
  __shared__ Smem sm;
  const int tid = threadIdx.x;
  const int lane = tid & 63;
  const int wid = tid >> 6;

  // XCD swizzle (5776 % 8 == 0)
  const int bid = blockIdx.x;
  const int item = (bid & 7) * (NBLK / 8) + (bid >> 3);
  const int b = item / (NTJ * NTT);
  const int r2 = item - b * (NTJ * NTT);
  const int jt = r2 / NTT, tt = r2 % NTT;
  const int tbase = tt * BT, jbase = jt * BJ;
  const float* unb = un + (size_t)b * 2 * NP;

  // stage coords into LDS (before first barrier)
  if (tid < 128) {
    const int tg = (tbase + tid < NP) ? tbase + tid : NP - 1;
    sm.tc2[tid] = make_float2(unb[tg], unb[NP + tg]);
  } else {
    const int i2 = tid - 128;
    const int jg = (jbase + i2 < NP) ? jbase + i2 : NP - 1;
    sm.jc2[i2] = make_float2(unb[jg], unb[NP + jg]);
  }

  // staging: waves 0-1 -> A (64 rows each), waves 2-3 -> B (64 rows each)
  // global rows are 256 B (fp8, k-permuted); kb selects a 64-B slice. Source slot pre-swizzled.
  const char* aSrc = (const char*)(tarQ + ((size_t)b * NPAD + tbase) * CDIM);
  const char* bSrc = (const char*)(refQ + ((size_t)b * NPAD + jbase) * CDIM);
  const int srcSlot = ((lane & 3) ^ ((lane >> 3) & 3)) * 16;
  const char* gl; int ldsOff;
  if (wid < 2) {
    gl = aSrc + (size_t)(wid * 64 + (lane >> 2)) * 256 + srcSlot;
    ldsOff = wid * 4096;
  } else {
    gl = bSrc + (size_t)((wid - 2) * 64 + (lane >> 2)) * 256 + srcSlot;
    ldsOff = 8192 + (wid - 2) * 4096;
  }

#define STAGE(buf, kb) do { \
    char* ldst = sm.bufs[buf] + ldsOff; \
    const char* gsp = gl + (kb) * 64; \
    _Pragma("unroll") for (int qq = 0; qq < 4; ++qq) \
      GLD16(ldst + qq * 1024, gsp + (size_t)qq * 4096); \
  } while (0)

  const int wr = wid >> 1, wc = wid & 1;   // wave tile: 64t x 64j
  const int l15 = lane & 15, h = lane >> 4;
  const int sx = (h ^ ((l15 >> 1) & 3)) << 4;   // swizzled 16-B slot (round-5 pattern)

  f32x4 acc[4][4];
#pragma unroll
  for (int fa = 0; fa < 4; ++fa)
#pragma unroll
    for (int fb = 0; fb < 4; ++fb) acc[fa][fb] = (f32x4){0.f, 0.f, 0.f, 0.f};

  // loop-invariant LDS read bases: fragment reads are base + imm offset
  const char* aptr = sm.bufs[0] + (wr * 64 + l15) * 64 + sx;
  const char* bptr = sm.bufs[0] + 8192 + (wc * 64 + l15) * 64 + sx;

  STAGE(0, 0);
  __syncthreads();
#pragma unroll
  for (int kb = 0; kb < 4; ++kb) {   // K = 256 = 4 * 64
    const int bo = (kb & 1) * 16384;
    if (kb < 3) STAGE((kb & 1) ^ 1, kb + 1);   // issue next-tile loads before compute
    longx2 bg[4];                               // one b128 = both K=32 slices
#pragma unroll
    for (int fb = 0; fb < 4; ++fb)
      bg[fb] = *(const longx2*)(bptr + bo + fb * 1024);
#pragma unroll
    for (int fa = 0; fa < 4; ++fa) {
      const longx2 af = *(const longx2*)(aptr + bo + fa * 1024);
#pragma unroll
      for (int fb = 0; fb < 4; ++fb)
        acc[fa][fb] = __builtin_amdgcn_mfma_f32_16x16x32_fp8_fp8(af.x, bg[fb].x, acc[fa][fb], 0, 0, 0);
#pragma unroll
      for (int fb = 0; fb < 4; ++fb)
        acc[fa][fb] = __builtin_amdgcn_mfma_f32_16x16x32_fp8_fp8(af.y, bg[fb].y, acc[fa][fb], 0, 0, 0);
    }
    if (kb < 3) __syncthreads();   // kb3: no LDS reuse below (red is in bufs[0], reads ended kb2)
  }

  // ---- epilogue: packed-key dual argmax (u32: [31:13]=bits(acc+512), [12:0]=8191-t) ----
  const float rf = (float)relax[0];
  float jx[4], jy[4];
#pragma unroll
  for (int fb = 0; fb < 4; ++fb) {
    const float2 jj = sm.jc2[wc * 64 + fb * 16 + l15];
    jx[fb] = jj.x; jy[fb] = jj.y;
  }
  unsigned int kA[4] = {0u, 0u, 0u, 0u}, kI[4] = {0u, 0u, 0u, 0u};
  const unsigned int tinv0 = (unsigned int)(8191 - tbase);

#define EPILOG(TAIL) \
  _Pragma("unroll") for (int fa = 0; fa < 4; ++fa) { \
    _Pragma("unroll") for (int i = 0; i < 4; ++i) { \
      const int tl = wr * 64 + fa * 16 + h * 4 + i; \
      const float2 tj = sm.tc2[tl]; \
      const unsigned int tinv = tinv0 - tl; \
      _Pragma("unroll") for (int fb = 0; fb < 4; ++fb) { \
        unsigned int key = (__float_as_uint(acc[fa][fb][i] + 512.f) & 0xFFFFE000u) | tinv; \
        if (TAIL && (tbase + tl >= NP)) key = 0u; \
        if (key > kA[fb]) kA[fb] = key; \
        const float mm = fmaxf(fabsf(tj.x - jx[fb]), fabsf(tj.y - jy[fb])); \
        const unsigned int keyI = (mm <= rf) ? 0u : key; \
        if (keyI > kI[fb]) kI[fb] = keyI; \
      } \
    } \
  }

  if (tbase + BT <= NP) { EPILOG(false) } else { EPILOG(true) }
#undef EPILOG

  // reduce over the 4 h-groups (disjoint t subsets, same j); red aliases bufs[0]
  uint2* red = (uint2*)sm.bufs[0];   // [2][128]; safe: bufs[0] reads ended at kb=2 barrier
#pragma unroll
  for (int fb = 0; fb < 4; ++fb) {
#pragma unroll
    for (int d = 16; d < 64; d <<= 1) {
      const unsigned int oA = __shfl_xor(kA[fb], d);
      const unsigned int oI = __shfl_xor(kI[fb], d);
      if (oA > kA[fb]) kA[fb] = oA;
      if (oI > kI[fb]) kI[fb] = oI;
    }
    if (h == 0) red[wr * 128 + wc * 64 + fb * 16 + l15] = make_uint2(kA[fb], kI[fb]);
  }
  __syncthreads();
  if (tid < 128) {
    const int jg = jbase + tid;
    if (jg < NP) {
      uint2 p0 = red[tid];
      const uint2 p1 = red[128 + tid];
      if (p1.x > p0.x) p0.x = p1.x;
      if (p1.y > p0.y) p0.y = p1.y;
      partial[((size_t)b * NP + jg) * NTT + tt] = p0;
    }
  }
#undef STAGE
}

// ---------------- fused combine + per-point loss + recall (wave per point) ----------------
__global__ __launch_bounds__(256)
void k_loss(const unsigned short* __restrict__ refB, const unsigned short* __restrict__ tarB,
            const float* __restrict__ un, const uint2* __restrict__ partial,
            float* __restrict__ loss_arr, float* __restrict__ rec_arr) {
  const int w = threadIdx.x >> 6, lane = threadIdx.x & 63;
  const int n = blockIdx.x * 4 + w;
  const int b = blockIdx.y;
  const int bn = b * NP + n;
  unsigned int kA = 0u, kI = 0u;
  if (lane < NTT) {
    const uint2 p = partial[(size_t)bn * NTT + lane];
    kA = p.x; kI = p.y;
  }
#pragma unroll
  for (int d = 1; d < 64; d <<= 1) {
    const unsigned int oA = __shfl_xor(kA, d);
    const unsigned int oI = __shfl_xor(kI, d);
    if (oA > kA) kA = oA;
    if (oI > kI) kI = oI;
  }
  const int nn  = 8191 - (int)(kA & 0x1FFFu);
  const int neg = 8191 - (int)(kI & 0x1FFFu);
  const ushort4 rv = *(const ushort4*)(refB + ((size_t)b * NPAD + n) * CDIM + lane * 4);
  const ushort4 tv = *(const ushort4*)(tarB + ((size_t)b * NPAD + n) * CDIM + lane * 4);
  const ushort4 gv = *(const ushort4*)(tarB + ((size_t)b * NPAD + neg) * CDIM + lane * 4);
  float dp = 0.f, dn = 0.f, d;
  d = bf2f(rv.x) - bf2f(tv.x) + 1e-6f; dp += d * d;
  d = bf2f(rv.y) - bf2f(tv.y) + 1e-6f; dp += d * d;
  d = bf2f(rv.z) - bf2f(tv.z) + 1e-6f; dp += d * d;
  d = bf2f(rv.w) - bf2f(tv.w) + 1e-6f; dp += d * d;
  d = bf2f(rv.x) - bf2f(gv.x) + 1e-6f; dn += d * d;
  d = bf2f(rv.y) - bf2f(gv.y) + 1e-6f; dn += d * d;
  d = bf2f(rv.z) - bf2f(gv.z) + 1e-6f; dn += d * d;
  d = bf2f(rv.w) - bf2f(gv.w) + 1e-6f; dn += d * d;
#pragma unroll
  for (int off = 1; off < 64; off <<= 1) {
    dp += __shfl_xor(dp, off);
    dn += __shfl_xor(dn, off);
  }
  if (lane == 0) {
    const float loss = fmaxf(sqrtf(dp) - sqrtf(dn) + 0.2f, 0.f);
    const float* unb = un + (size_t)b * 2 * NP;
    const float rec = (unb[nn] == unb[n] && unb[NP + nn] == unb[NP + n]) ? 1.f : 0.f;
    loss_arr[bn] = loss;
    rec_arr[bn] = rec;
  }
}

// ---------------- final deterministic reduce ----------------
__global__ __launch_bounds__(256)
void k_finalize(const float* __restrict__ loss_arr, const float* __restrict__ rec_arr,
                float* __restrict__ out) {
  __shared__ float l[256], rr[256];
  float ls = 0.f, rs = 0.f;
  for (int i = threadIdx.x; i < BQ * NP; i += 256) { ls += loss_arr[i]; rs += rec_arr[i]; }
  l[threadIdx.x] = ls;
  rr[threadIdx.x] = rs;
  __syncthreads();
  for (int s = 128; s > 0; s >>= 1) {
    if (threadIdx.x < s) { l[threadIdx.x] += l[threadIdx.x + s]; rr[threadIdx.x] += rr[threadIdx.x + s]; }
    __syncthreads();
  }
  if (threadIdx.x == 0) {
    out[0] = l[0] / (float)(BQ * NP);
    out[1] = rr[0] / (float)(BQ * NP);
  }
}

extern "C" void kernel_launch(void* const* d_in, const int* in_sizes, int n_in,
                              void* d_out, int out_size, void* d_ws, size_t ws_size,
                              hipStream_t stream) {
  const float* src  = (const float*)d_in[0];
  const float* tgt  = (const float*)d_in[1];
  const float* spts = (const float*)d_in[2];
  const float* tpts = (const float*)d_in[3];
  const float* un   = (const float*)d_in[4];
  const int* relax  = (const int*)d_in[5];

  char* ws = (char*)d_ws;
  unsigned short* desT     = (unsigned short*)(ws + WS_DEST);
  uint2*          partial  = (uint2*)(ws + WS_PART);   // aliases desT (dead by then)
  unsigned short* refB     = (unsigned short*)(ws + WS_REFB);
  unsigned short* tarB     = (unsigned short*)(ws + WS_TARB);
  unsigned char*  refQ     = (unsigned char*)(ws + WS_REFQ);
  unsigned char*  tarQ     = (unsigned char*)(ws + WS_TARQ);
  float*          loss_arr = (float*)(ws + WS_LOSS);
  float*          rec_arr  = (float*)(ws + WS_REC);
  float*          out      = (float*)d_out;

  k_transpose<<<dim3(NP / 32, CDIM / 64, 8), dim3(32, 8), 0, stream>>>(src, tgt, desT);
  k_sample<<<dim3(NPAD / 4, BQ, 2), 256, 0, stream>>>(desT, spts, tpts, refB, tarB, refQ, tarQ);
  k_mfma_argmax<<<NBLK, 256, 0, stream>>>(tarQ, refQ, un, relax, partial);
  k_loss<<<dim3(NP / 4, BQ), 256, 0, stream>>>(refB, tarB, un, partial, loss_arr, rec_arr);
  k_finalize<<<1, 256, 0, stream>>>(loss_arr, rec_arr, out);
}